// Round 5
// baseline (937.066 us; speedup 1.0000x reference)
//
#include <hip/hip_runtime.h>

#define NPTS 65536
#define DIM  512
#define HID  256
#define KCL  16
#define NLVL 3
#define NCLS 64
#define NSEG (NCLS*KCL)
#define EPSF 1e-5f

typedef __bf16 bf16_t;
typedef bf16_t bf16x4 __attribute__((ext_vector_type(4)));
typedef bf16_t bf16x8 __attribute__((ext_vector_type(8)));
typedef float  f32x4  __attribute__((ext_vector_type(4)));

#define LDA 40   // padded LDS row stride in bf16 units

// ============================ W1 split+transpose (once): W1[l][k][j] -> [(l*256+j)][k] ====
__global__ __launch_bounds__(256) void wsplit_kernel(
    const float* __restrict__ w1, bf16_t* __restrict__ hiT, bf16_t* __restrict__ loT)
{
  int gid = blockIdx.x * 256 + threadIdx.x;   // 0..393215
  int n = gid >> 9, k = gid & 511;
  int l = n >> 8, j = n & 255;
  float v = w1[l*DIM*HID + k*HID + j];
  bf16_t h = (bf16_t)v;
  hiT[gid] = h;
  loT[gid] = (bf16_t)(v - (float)h);
}

// ============================ ref-W split+transpose, both weights in one launch ===========
__global__ __launch_bounds__(256) void wsplit2_kernel(
    const float* __restrict__ w1, const float* __restrict__ w2,
    bf16_t* __restrict__ h1, bf16_t* __restrict__ l1,
    bf16_t* __restrict__ h2, bf16_t* __restrict__ l2)
{
  const int per = NLVL*DIM*DIM;
  int gid = blockIdx.x * 256 + threadIdx.x;   // 0..2*per-1
  const float* w = (gid < per) ? w1 : w2;
  bf16_t* hh = (gid < per) ? h1 : h2;
  bf16_t* ll = (gid < per) ? l1 : l2;
  int g2 = (gid < per) ? gid : gid - per;
  int n512 = g2 >> 9, k = g2 & 511;
  int l = n512 >> 9, n = n512 & 511;
  float v = w[(size_t)l*DIM*DIM + (size_t)k*DIM + n];
  bf16_t h = (bf16_t)v;
  hh[g2] = h;
  ll[g2] = (bf16_t)(v - (float)h);
}

// ============================ cluster-head W2 split+transpose: [l][k][k2] -> [l][k2][k] ===
__global__ __launch_bounds__(256) void wsplitW2_kernel(
    const float* __restrict__ w2, bf16_t* __restrict__ hiT, bf16_t* __restrict__ loT)
{
  int gid = blockIdx.x * 256 + threadIdx.x;   // 0..NLVL*KCL*HID-1 = 12287
  int l = gid >> 12, rem = gid & 4095;
  int k2 = rem >> 8, k = rem & 255;
  float v = w2[(size_t)l*HID*KCL + k*KCL + k2];
  bf16_t h = (bf16_t)v;
  hiT[gid] = h;
  loT[gid] = (bf16_t)(v - (float)h);
}

// ============================ big GEMM: G = feat @ W1 (128x128 tile, hi/lo 3-term) ========
// Hoisted over all levels: grid (NPTS/128, NLVL*HID/128) — the measured-best geometry
// (64.7 us/level-equivalent, MfmaUtil 35%). Per-level fallback uses grid (NPTS/128, 2).
__global__ __launch_bounds__(256, 2) void gemm128_kernel(
    const float* __restrict__ feat,
    const bf16_t* __restrict__ BhiT, const bf16_t* __restrict__ BloT,
    float* __restrict__ G, int ldg)
{
  __shared__ __align__(16) bf16_t Ahi[128*LDA];
  __shared__ __align__(16) bf16_t Alo[128*LDA];
  __shared__ __align__(16) bf16_t Bhi[128*LDA];
  __shared__ __align__(16) bf16_t Blo[128*LDA];

  const int t = threadIdx.x;
  const int row0 = blockIdx.x * 128, col0 = blockIdx.y * 128;
  const int w = t >> 6, lane = t & 63;
  const int wm = w & 1, wn = w >> 1;
  const int fm = lane & 15, fq = lane >> 4;

  f32x4 acc[4][4];
  #pragma unroll
  for (int i = 0; i < 4; i++)
    #pragma unroll
    for (int j = 0; j < 4; j++)
      #pragma unroll
      for (int r = 0; r < 4; r++) acc[i][j][r] = 0.f;

  for (int kc = 0; kc < DIM; kc += 32) {
    __syncthreads();
    #pragma unroll
    for (int p = 0; p < 4; p++) {
      int idx = t + 256*p;
      int r = idx >> 3, c = idx & 7;
      float4 v = *(const float4*)&feat[(size_t)(row0 + r)*DIM + kc + c*4];
      bf16x4 hi, lo;
      hi[0] = (bf16_t)v.x; lo[0] = (bf16_t)(v.x - (float)hi[0]);
      hi[1] = (bf16_t)v.y; lo[1] = (bf16_t)(v.y - (float)hi[1]);
      hi[2] = (bf16_t)v.z; lo[2] = (bf16_t)(v.z - (float)hi[2]);
      hi[3] = (bf16_t)v.w; lo[3] = (bf16_t)(v.w - (float)hi[3]);
      *(bf16x4*)&Ahi[r*LDA + c*4] = hi;
      *(bf16x4*)&Alo[r*LDA + c*4] = lo;
    }
    #pragma unroll
    for (int p = 0; p < 2; p++) {
      int idx = t + 256*p;
      int n = idx >> 2, c = idx & 3;
      *(bf16x8*)&Bhi[n*LDA + c*8] = *(const bf16x8*)&BhiT[(size_t)(col0 + n)*DIM + kc + c*8];
      *(bf16x8*)&Blo[n*LDA + c*8] = *(const bf16x8*)&BloT[(size_t)(col0 + n)*DIM + kc + c*8];
    }
    __syncthreads();

    bf16x8 ah[4], al[4], bh[4], bl[4];
    #pragma unroll
    for (int mt = 0; mt < 4; mt++) {
      int rr = (wm*64 + mt*16 + fm)*LDA + fq*8;
      ah[mt] = *(bf16x8*)&Ahi[rr];
      al[mt] = *(bf16x8*)&Alo[rr];
    }
    #pragma unroll
    for (int nt = 0; nt < 4; nt++) {
      int rr = (wn*64 + nt*16 + fm)*LDA + fq*8;
      bh[nt] = *(bf16x8*)&Bhi[rr];
      bl[nt] = *(bf16x8*)&Blo[rr];
    }
    #pragma unroll
    for (int mt = 0; mt < 4; mt++)
      #pragma unroll
      for (int nt = 0; nt < 4; nt++) {
        acc[mt][nt] = __builtin_amdgcn_mfma_f32_16x16x32_bf16(ah[mt], bh[nt], acc[mt][nt], 0, 0, 0);
        acc[mt][nt] = __builtin_amdgcn_mfma_f32_16x16x32_bf16(ah[mt], bl[nt], acc[mt][nt], 0, 0, 0);
        acc[mt][nt] = __builtin_amdgcn_mfma_f32_16x16x32_bf16(al[mt], bh[nt], acc[mt][nt], 0, 0, 0);
      }
  }

  #pragma unroll
  for (int mt = 0; mt < 4; mt++)
    #pragma unroll
    for (int nt = 0; nt < 4; nt++) {
      int col = col0 + wn*64 + nt*16 + fm;
      int rowb = row0 + wm*64 + mt*16 + fq*4;
      #pragma unroll
      for (int r = 0; r < 4; r++)
        G[(size_t)(rowb + r)*ldg + col] = acc[mt][nt][r];
    }
}

// ============================ assign3: no-LDS MFMA assign over G slab (proven R3) =========
// Wave w handles rows [row0+w*16, +16). A-frag h and B-frag W2T load directly in MFMA
// fragment order (A row=fm, k=fq*8+j; B col=fm, k=fq*8+j). logits C-frag: row=fq*4+r,
// col(k2)=fm. Argmax via width-16 shuffle, first-max tie-break.
__global__ __launch_bounds__(256) void assign3_kernel(
    const float* __restrict__ Gl, int ldg,                         // [NPTS][ldg]
    const bf16_t* __restrict__ w2hT, const bf16_t* __restrict__ w2lT,  // [KCL][HID]
    const float* __restrict__ offsrc, int ldo,
    const int* __restrict__ labels,
    const float* __restrict__ pb2,
    int* __restrict__ asg, int* __restrict__ cnt)
{
  __shared__ int labs[64];
  const int t = threadIdx.x;
  const int w = t >> 6, lane = t & 63;
  const int fm = lane & 15, fq = lane >> 4;
  const int row0 = blockIdx.x * 64;
  if (t < 64) labs[t] = labels[row0 + t];
  __syncthreads();

  const int row = w*16 + fm;            // block-local row this lane's A-frag serves
  const int lab = labs[row];
  const float pv = pb2[fm];
  const float* grow = &Gl[(size_t)(row0 + row)*ldg];
  const float* orow = &offsrc[(size_t)lab*ldo];

  f32x4 lg = {0.f, 0.f, 0.f, 0.f};
  #pragma unroll
  for (int k0 = 0; k0 < HID; k0 += 32) {
    int kb = k0 + fq*8;
    f32x4 g0 = *(const f32x4*)&grow[kb];
    f32x4 g1 = *(const f32x4*)&grow[kb + 4];
    f32x4 o0 = *(const f32x4*)&orow[kb];
    f32x4 o1 = *(const f32x4*)&orow[kb + 4];
    bf16x8 ah, al;
    #pragma unroll
    for (int j = 0; j < 4; j++) {
      float h0 = fmaxf(g0[j] + o0[j], 0.f);
      float h1 = fmaxf(g1[j] + o1[j], 0.f);
      bf16_t c0 = (bf16_t)h0; ah[j]   = c0; al[j]   = (bf16_t)(h0 - (float)c0);
      bf16_t c1 = (bf16_t)h1; ah[4+j] = c1; al[4+j] = (bf16_t)(h1 - (float)c1);
    }
    bf16x8 bh = *(const bf16x8*)&w2hT[fm*HID + kb];
    bf16x8 bl = *(const bf16x8*)&w2lT[fm*HID + kb];
    lg = __builtin_amdgcn_mfma_f32_16x16x32_bf16(ah, bh, lg, 0, 0, 0);
    lg = __builtin_amdgcn_mfma_f32_16x16x32_bf16(ah, bl, lg, 0, 0, 0);
    lg = __builtin_amdgcn_mfma_f32_16x16x32_bf16(al, bh, lg, 0, 0, 0);
  }

  #pragma unroll
  for (int r = 0; r < 4; r++) {
    float v = lg[r] + pv;
    int idx = fm;
    #pragma unroll
    for (int ofs = 8; ofs > 0; ofs >>= 1) {
      float ov = __shfl_xor(v, ofs, 16);
      int   oi = __shfl_xor(idx, ofs, 16);
      if (ov > v || (ov == v && oi < idx)) { v = ov; idx = oi; }
    }
    if (fm == 0) {
      int rloc = w*16 + fq*4 + r;
      asg[row0 + rloc] = idx;
      atomicAdd(&cnt[labs[rloc]*KCL + idx], 1);
    }
  }
}

// ============================ refine GEMM: 64x64 tile, 4-term hi/lo, fused pre-ops ========
// mode 1: A[row][k] = (sums[row][k] + cnt[row]*off[cls][k]) / max(cnt,1)
// mode 2: A[row][k] = relu((Y1[row][k] + b1[k] - mS[row]) * rS[row] * g[k] + bb[k])
__global__ __launch_bounds__(256) void gemm64_kernel(
    const float* __restrict__ Asrc,
    const bf16_t* __restrict__ BhiT, const bf16_t* __restrict__ BloT,
    float* __restrict__ C, int mode,
    const int* __restrict__ cnt, const float* __restrict__ off,
    const float* __restrict__ b1, const float* __restrict__ g,
    const float* __restrict__ bb,
    const float* __restrict__ mS, const float* __restrict__ rS)
{
  __shared__ __align__(16) bf16_t Ahi[64*LDA];
  __shared__ __align__(16) bf16_t Alo[64*LDA];
  __shared__ __align__(16) bf16_t Bhi[64*LDA];
  __shared__ __align__(16) bf16_t Blo[64*LDA];
  __shared__ float rm[64], rr_[64];

  const int t = threadIdx.x;
  const int row0 = blockIdx.x * 64, col0 = blockIdx.y * 64;
  const int w = t >> 6, lane = t & 63;
  const int wm = w & 1, wn = w >> 1;
  const int fm = lane & 15, fq = lane >> 4;

  if (t < 64) {
    if (mode == 1) {
      int n = cnt[row0 + t];
      rm[t] = (float)n;
      rr_[t] = 1.f / fmaxf((float)n, 1.f);
    } else {
      rm[t] = mS[row0 + t];
      rr_[t] = rS[row0 + t];
    }
  }

  f32x4 acc[2][2];
  #pragma unroll
  for (int i = 0; i < 2; i++)
    #pragma unroll
    for (int j = 0; j < 2; j++)
      #pragma unroll
      for (int r = 0; r < 4; r++) acc[i][j][r] = 0.f;

  for (int kc = 0; kc < DIM; kc += 32) {
    __syncthreads();
    #pragma unroll
    for (int p = 0; p < 2; p++) {
      int idx = t + 256*p;
      int r = idx >> 3, c = idx & 7;
      float4 v = *(const float4*)&Asrc[(size_t)(row0 + r)*DIM + kc + c*4];
      if (mode == 1) {
        int cls = (row0 + r) >> 4;
        float4 o = *(const float4*)&off[(size_t)cls*DIM + kc + c*4];
        float n = rm[r], inv = rr_[r];
        v.x = (v.x + n*o.x) * inv; v.y = (v.y + n*o.y) * inv;
        v.z = (v.z + n*o.z) * inv; v.w = (v.w + n*o.w) * inv;
      } else {
        float4 B1 = *(const float4*)&b1[kc + c*4];
        float4 G4 = *(const float4*)&g[kc + c*4];
        float4 BB = *(const float4*)&bb[kc + c*4];
        float m = rm[r], rs = rr_[r];
        v.x = fmaxf((v.x + B1.x - m)*rs*G4.x + BB.x, 0.f);
        v.y = fmaxf((v.y + B1.y - m)*rs*G4.y + BB.y, 0.f);
        v.z = fmaxf((v.z + B1.z - m)*rs*G4.z + BB.z, 0.f);
        v.w = fmaxf((v.w + B1.w - m)*rs*G4.w + BB.w, 0.f);
      }
      bf16x4 hi, lo;
      hi[0] = (bf16_t)v.x; lo[0] = (bf16_t)(v.x - (float)hi[0]);
      hi[1] = (bf16_t)v.y; lo[1] = (bf16_t)(v.y - (float)hi[1]);
      hi[2] = (bf16_t)v.z; lo[2] = (bf16_t)(v.z - (float)hi[2]);
      hi[3] = (bf16_t)v.w; lo[3] = (bf16_t)(v.w - (float)hi[3]);
      *(bf16x4*)&Ahi[r*LDA + c*4] = hi;
      *(bf16x4*)&Alo[r*LDA + c*4] = lo;
    }
    {
      int n = t >> 2, kof = (t & 3)*8;
      *(bf16x8*)&Bhi[n*LDA + kof] = *(const bf16x8*)&BhiT[(size_t)(col0 + n)*DIM + kc + kof];
      *(bf16x8*)&Blo[n*LDA + kof] = *(const bf16x8*)&BloT[(size_t)(col0 + n)*DIM + kc + kof];
    }
    __syncthreads();

    bf16x8 ah[2], al[2], bh[2], bl[2];
    #pragma unroll
    for (int mt = 0; mt < 2; mt++) {
      int idx = (wm*32 + mt*16 + fm)*LDA + fq*8;
      ah[mt] = *(bf16x8*)&Ahi[idx];
      al[mt] = *(bf16x8*)&Alo[idx];
    }
    #pragma unroll
    for (int nt = 0; nt < 2; nt++) {
      int idx = (wn*32 + nt*16 + fm)*LDA + fq*8;
      bh[nt] = *(bf16x8*)&Bhi[idx];
      bl[nt] = *(bf16x8*)&Blo[idx];
    }
    #pragma unroll
    for (int mt = 0; mt < 2; mt++)
      #pragma unroll
      for (int nt = 0; nt < 2; nt++) {
        acc[mt][nt] = __builtin_amdgcn_mfma_f32_16x16x32_bf16(ah[mt], bh[nt], acc[mt][nt], 0, 0, 0);
        acc[mt][nt] = __builtin_amdgcn_mfma_f32_16x16x32_bf16(ah[mt], bl[nt], acc[mt][nt], 0, 0, 0);
        acc[mt][nt] = __builtin_amdgcn_mfma_f32_16x16x32_bf16(al[mt], bh[nt], acc[mt][nt], 0, 0, 0);
        acc[mt][nt] = __builtin_amdgcn_mfma_f32_16x16x32_bf16(al[mt], bl[nt], acc[mt][nt], 0, 0, 0);
      }
  }

  #pragma unroll
  for (int mt = 0; mt < 2; mt++)
    #pragma unroll
    for (int nt = 0; nt < 2; nt++) {
      int col = col0 + wn*32 + nt*16 + fm;
      int rowb = row0 + wm*32 + mt*16 + fq*4;
      #pragma unroll
      for (int r = 0; r < 4; r++)
        C[(size_t)(rowb + r)*DIM + col] = acc[mt][nt][r];
    }
}

// ============================ LN stats of (Y1 + b1) per row ===============================
__global__ __launch_bounds__(256) void lnstats_kernel(
    const float* __restrict__ Y1, const float* __restrict__ b1,
    float* __restrict__ mS, float* __restrict__ rS)
{
  int r = blockIdx.x, t = threadIdx.x;
  float x0 = Y1[(size_t)r*DIM + t]       + b1[t];
  float x1 = Y1[(size_t)r*DIM + t + 256] + b1[t + 256];
  float s1 = x0 + x1, s2 = x0*x0 + x1*x1;
  #pragma unroll
  for (int ofs = 32; ofs > 0; ofs >>= 1) {
    s1 += __shfl_xor(s1, ofs);
    s2 += __shfl_xor(s2, ofs);
  }
  __shared__ float r1[4], r2[4];
  int lane = t & 63, w = t >> 6;
  if (lane == 0) { r1[w] = s1; r2[w] = s2; }
  __syncthreads();
  if (t == 0) {
    s1 = r1[0] + r1[1] + r1[2] + r1[3];
    s2 = r2[0] + r2[1] + r2[2] + r2[3];
    float m = s1 * (1.f/512.f);
    float var = s2 * (1.f/512.f) - m*m;
    mS[r] = m;
    rS[r] = rsqrtf(var + EPSF);
  }
}

// ============================ offW1b[c][j] = off[c]@W1_l[:,j] + b1[j] (l=0 handled by ldo=0)
// fused: lp[c] = mean over non-empty k of Y2 + b2; off += lp; then next-level offgemm.
__global__ __launch_bounds__(256) void protoOffgemm_kernel(
    const float* __restrict__ Y2, const float* __restrict__ b2,
    const int* __restrict__ cnt, float* __restrict__ off, float* __restrict__ lp_out,
    const float* __restrict__ w1next, const float* __restrict__ b1next,
    float* __restrict__ offW1b)
{
  __shared__ float offs[DIM];
  int c = blockIdx.x, t = threadIdx.x;
  int nes = 0;
  #pragma unroll
  for (int k = 0; k < KCL; k++) nes += (cnt[c*KCL + k] > 0);
  float inv = 1.f / (float)nes;
  #pragma unroll
  for (int h = 0; h < 2; h++) {
    int d = t + h*256;
    float s = 0.f;
    #pragma unroll
    for (int k = 0; k < KCL; k++)
      if (cnt[c*KCL + k] > 0) s += Y2[(size_t)(c*KCL + k)*DIM + d];
    float lp = s * inv + b2[d];
    lp_out[c*DIM + d] = lp;
    float on = off[c*DIM + d] + lp;
    off[c*DIM + d] = on;
    offs[d] = on;
  }
  if (w1next == nullptr) return;
  __syncthreads();
  float a = 0.f;
  #pragma unroll 4
  for (int d = 0; d < DIM; d++)
    a = fmaf(offs[d], w1next[d*HID + t], a);
  offW1b[c*HID + t] = a + b1next[t];
}

// ============================ exclusive scan (shuffle-based) ==============================
__global__ void scan_kernel(const int* __restrict__ cnt, int* __restrict__ seg_st,
                            int* __restrict__ cursor)
{
  int t = threadIdx.x;
  int4 v = *(const int4*)&cnt[t*4];
  int a0 = v.x, a1 = v.x + v.y, a2 = a1 + v.z, tot = a2 + v.w;
  int lane = t & 63, w = t >> 6;
  int sc = tot;
  #pragma unroll
  for (int ofs = 1; ofs < 64; ofs <<= 1) {
    int u = __shfl_up(sc, ofs);
    if (lane >= ofs) sc += u;
  }
  __shared__ int wt[4];
  if (lane == 63) wt[w] = sc;
  __syncthreads();
  int base = 0;
  #pragma unroll
  for (int i = 0; i < 4; i++) if (i < w) base += wt[i];
  int excl = base + sc - tot;
  seg_st[t*4 + 1] = excl + a0;
  seg_st[t*4 + 2] = excl + a1;
  seg_st[t*4 + 3] = excl + a2;
  seg_st[t*4 + 4] = excl + tot;
  if (t == 0) seg_st[0] = 0;
  int4 cur = {excl, excl + a0, excl + a1, excl + a2};
  *(int4*)&cursor[t*4] = cur;
}

// ============================ scatter rows into per-segment sorted lists ==================
__global__ __launch_bounds__(256) void scatter_kernel(
    const int* __restrict__ labels, const int* __restrict__ asg,
    int* __restrict__ cursor, int* __restrict__ rowlist, int* __restrict__ seglist)
{
  int i = blockIdx.x * 256 + threadIdx.x;
  int seg = labels[i]*KCL + asg[i];
  int pos = atomicAdd(&cursor[seg], 1);
  rowlist[pos] = i;
  seglist[pos] = seg;
}

// ============================ balanced segmented sums over sorted rowlist =================
__global__ __launch_bounds__(256) void means3_kernel(
    const float* __restrict__ feat, const int* __restrict__ rowlist,
    const int* __restrict__ seglist, float* __restrict__ sums)
{
  __shared__ int rows[64];
  __shared__ int segs[65];
  int t = threadIdx.x;
  int i0 = blockIdx.x * 64;
  int col = blockIdx.y * 256 + t;
  if (t < 64) { rows[t] = rowlist[i0 + t]; segs[t] = seglist[i0 + t]; }
  if (t == 64) segs[64] = -1;
  __syncthreads();
  float acc = 0.f;
  for (int base = 0; base < 64; base += 16) {
    float v[16];
    #pragma unroll
    for (int j = 0; j < 16; j++)
      v[j] = feat[(size_t)rows[base + j]*DIM + col];
    #pragma unroll
    for (int j = 0; j < 16; j++) {
      acc += v[j];
      if (segs[base + j] != segs[base + j + 1]) {
        atomicAdd(&sums[(size_t)segs[base + j]*DIM + col], acc);
        acc = 0.f;
      }
    }
  }
}

// ============================ final stage 1: Hacc += comb[64x1536] @ cw1 (K-split) ========
__global__ __launch_bounds__(256) void fgemm1_kernel(
    const float* __restrict__ lp_all, const float* __restrict__ cw1,
    float* __restrict__ Hacc)
{
  __shared__ float As[64*132];
  __shared__ float Ws[128*64];
  int t = threadIdx.x;
  int nc = blockIdx.x * 64, kc = blockIdx.y * 128;

  #pragma unroll
  for (int p = 0; p < 8; p++) {
    int i = t + 256*p;
    int m = i >> 5, k0 = (i & 31) << 2;
    int k = kc + k0;
    int l = k >> 9, d = k & 511;
    *(float4*)&As[m*132 + k0] = *(const float4*)&lp_all[(size_t)(l*NCLS + m)*DIM + d];
  }
  #pragma unroll
  for (int p = 0; p < 8; p++) {
    int i = t + 256*p;
    int k = i >> 4, n0 = (i & 15) << 2;
    *(float4*)&Ws[k*64 + n0] = *(const float4*)&cw1[(size_t)(kc + k)*DIM + nc + n0];
  }
  __syncthreads();

  int tn = (t & 15) * 4, tmg = (t >> 4) * 4;
  float acc[4][4];
  #pragma unroll
  for (int i = 0; i < 4; i++)
    #pragma unroll
    for (int j = 0; j < 4; j++) acc[i][j] = 0.f;

  for (int k = 0; k < 128; k += 4) {
    float4 a[4], w[4];
    #pragma unroll
    for (int i = 0; i < 4; i++) a[i] = *(float4*)&As[(tmg + i)*132 + k];
    #pragma unroll
    for (int j = 0; j < 4; j++) w[j] = *(float4*)&Ws[(k + j)*64 + tn];
    #pragma unroll
    for (int kk = 0; kk < 4; kk++) {
      float wv[4] = {w[kk].x, w[kk].y, w[kk].z, w[kk].w};
      float av[4] = {a[0][kk], a[1][kk], a[2][kk], a[3][kk]};
      #pragma unroll
      for (int i = 0; i < 4; i++)
        #pragma unroll
        for (int j = 0; j < 4; j++)
          acc[i][j] = fmaf(av[i], wv[j], acc[i][j]);
    }
  }
  #pragma unroll
  for (int i = 0; i < 4; i++)
    #pragma unroll
    for (int j = 0; j < 4; j++)
      atomicAdd(&Hacc[(size_t)(tmg + i)*DIM + nc + tn + j], acc[i][j]);
}

// ============================ final stage 2: Oacc += relu(Hacc+cb1) @ cw2 (K-split) =======
__global__ __launch_bounds__(256) void fgemm2_kernel(
    const float* __restrict__ Hacc, const float* __restrict__ cb1,
    const float* __restrict__ cw2, float* __restrict__ Oacc)
{
  __shared__ float As[64*132];
  __shared__ float Ws[128*64];
  int t = threadIdx.x;
  int nc = blockIdx.x * 64, kc = blockIdx.y * 128;

  #pragma unroll
  for (int p = 0; p < 8; p++) {
    int i = t + 256*p;
    int m = i >> 5, k0 = (i & 31) << 2;
    float4 v = *(const float4*)&Hacc[(size_t)m*DIM + kc + k0];
    float4 b = *(const float4*)&cb1[kc + k0];
    v.x = fmaxf(v.x + b.x, 0.f); v.y = fmaxf(v.y + b.y, 0.f);
    v.z = fmaxf(v.z + b.z, 0.f); v.w = fmaxf(v.w + b.w, 0.f);
    *(float4*)&As[m*132 + k0] = v;
  }
  #pragma unroll
  for (int p = 0; p < 8; p++) {
    int i = t + 256*p;
    int k = i >> 4, n0 = (i & 15) << 2;
    *(float4*)&Ws[k*64 + n0] = *(const float4*)&cw2[(size_t)(kc + k)*DIM + nc + n0];
  }
  __syncthreads();

  int tn = (t & 15) * 4, tmg = (t >> 4) * 4;
  float acc[4][4];
  #pragma unroll
  for (int i = 0; i < 4; i++)
    #pragma unroll
    for (int j = 0; j < 4; j++) acc[i][j] = 0.f;

  for (int k = 0; k < 128; k += 4) {
    float4 a[4], w[4];
    #pragma unroll
    for (int i = 0; i < 4; i++) a[i] = *(float4*)&As[(tmg + i)*132 + k];
    #pragma unroll
    for (int j = 0; j < 4; j++) w[j] = *(float4*)&Ws[(k + j)*64 + tn];
    #pragma unroll
    for (int kk = 0; kk < 4; kk++) {
      float wv[4] = {w[kk].x, w[kk].y, w[kk].z, w[kk].w};
      float av[4] = {a[0][kk], a[1][kk], a[2][kk], a[3][kk]};
      #pragma unroll
      for (int i = 0; i < 4; i++)
        #pragma unroll
        for (int j = 0; j < 4; j++)
          acc[i][j] = fmaf(av[i], wv[j], acc[i][j]);
    }
  }
  #pragma unroll
  for (int i = 0; i < 4; i++)
    #pragma unroll
    for (int j = 0; j < 4; j++)
      atomicAdd(&Oacc[(size_t)(tmg + i)*DIM + nc + tn + j], acc[i][j]);
}

// ============================ final stage 3: out = Oacc + cb2 =============================
__global__ __launch_bounds__(256) void fbias_kernel(
    const float* __restrict__ Oacc, const float* __restrict__ cb2,
    float* __restrict__ out)
{
  int gi = blockIdx.x * 256 + threadIdx.x;
  out[gi] = Oacc[gi] + cb2[gi & 511];
}

// ============================ launch ======================================================
extern "C" void kernel_launch(void* const* d_in, const int* in_sizes, int n_in,
                              void* d_out, int out_size, void* d_ws, size_t ws_size,
                              hipStream_t stream) {
  const float* feat   = (const float*)d_in[0];
  const int*   labels = (const int*)d_in[1];
  const float* ch_w1  = (const float*)d_in[2];
  const float* ch_b1  = (const float*)d_in[3];
  const float* ch_w2  = (const float*)d_in[4];
  const float* ch_b2  = (const float*)d_in[5];
  const float* ref_w1 = (const float*)d_in[6];
  const float* ref_b1 = (const float*)d_in[7];
  const float* ln_g   = (const float*)d_in[8];
  const float* ln_b   = (const float*)d_in[9];
  const float* ref_w2 = (const float*)d_in[10];
  const float* ref_b2 = (const float*)d_in[11];
  const float* cw1    = (const float*)d_in[12];
  const float* cb1    = (const float*)d_in[13];
  const float* cw2    = (const float*)d_in[14];
  const float* cb2    = (const float*)d_in[15];
  float* out = (float*)d_out;

  float* wsf = (float*)d_ws;
  float* off    = wsf;                 // 32768
  float* lp_all = off + 32768;         // 98304
  float* sums   = lp_all + 98304;      // 524288
  int*   cnt_i  = (int*)(sums + 524288); // 1024 (adjacent to sums: single memset)
  float* offW1b = sums + 524288 + 1024; // 16384
  float* Hacc   = offW1b + 16384;      // 32768
  float* Oacc   = Hacc + 32768;        // 32768
  float* Y1     = Oacc + 32768;        // 524288
  float* Y2     = Y1 + 524288;         // 524288
  float* mS     = Y2 + 524288;         // 1024
  float* rS     = mS + 1024;           // 1024
  float* G      = rS + 1024;           // variable size

  size_t base_f  = (size_t)(G - wsf);
  size_t g_hoist = (size_t)NPTS * (NLVL*HID);
  size_t g_level = (size_t)NPTS * HID;
  size_t bf16_f  = ((size_t)2*NLVL*HID*DIM + (size_t)4*NLVL*DIM*DIM
                    + (size_t)2*NLVL*KCL*HID) / 2;
  size_t int_f   = 3*(size_t)NPTS + 1040 + NSEG;
  bool hoist = ws_size >= (base_f + g_hoist + bf16_f + int_f + 1024) * 4;
  size_t g_elems = hoist ? g_hoist : g_level;
  int ldg = hoist ? NLVL*HID : HID;

  bf16_t* whiT  = (bf16_t*)(G + g_elems);
  bf16_t* wloT  = whiT + (size_t)NLVL*HID*DIM;
  bf16_t* r1hiT = wloT + (size_t)NLVL*HID*DIM;
  bf16_t* r1loT = r1hiT + (size_t)NLVL*DIM*DIM;
  bf16_t* r2hiT = r1loT + (size_t)NLVL*DIM*DIM;
  bf16_t* r2loT = r2hiT + (size_t)NLVL*DIM*DIM;
  bf16_t* w2hT  = r2loT + (size_t)NLVL*DIM*DIM;     // [NLVL][KCL][HID]
  bf16_t* w2lT  = w2hT + (size_t)NLVL*KCL*HID;
  int* asg     = (int*)(w2lT + (size_t)NLVL*KCL*HID);
  int* rowlist = asg + NPTS;
  int* seglist = rowlist + NPTS;
  int* seg_st  = seglist + NPTS;       // 1025 used, 1040 reserved
  int* cursor  = seg_st + 1040;        // NSEG

  hipMemsetAsync(off, 0, NCLS*DIM*sizeof(float), stream);

  wsplit_kernel<<<NLVL*HID*DIM/256, 256, 0, stream>>>(ch_w1, whiT, wloT);
  wsplit2_kernel<<<2*NLVL*DIM*DIM/256, 256, 0, stream>>>(
      ref_w1, ref_w2, r1hiT, r1loT, r2hiT, r2loT);
  wsplitW2_kernel<<<NLVL*KCL*HID/256, 256, 0, stream>>>(ch_w2, w2hT, w2lT);

  if (hoist)
    gemm128_kernel<<<dim3(NPTS/128, NLVL*HID/128), 256, 0, stream>>>(
        feat, whiT, wloT, G, ldg);

  for (int l = 0; l < NLVL; l++) {
    hipMemsetAsync(sums, 0, (NSEG*DIM + NSEG)*sizeof(float), stream);  // sums + cnt_i

    if (!hoist)
      gemm128_kernel<<<dim3(NPTS/128, HID/128), 256, 0, stream>>>(
          feat, whiT + (size_t)l*HID*DIM, wloT + (size_t)l*HID*DIM, G, ldg);

    // l=0: off==0 -> offW1b[c] == b1 for all c -> read b1 with row-stride 0
    const float* offsrc = (l == 0) ? ch_b1 : offW1b;
    int ldo = (l == 0) ? 0 : HID;

    // assign: logits = relu(G_l+off) @ W2 via no-LDS MFMA, argmax -> asg, cnt
    assign3_kernel<<<NPTS/64, 256, 0, stream>>>(
        hoist ? (G + (size_t)l*HID) : G, ldg,
        w2hT + (size_t)l*KCL*HID, w2lT + (size_t)l*KCL*HID,
        offsrc, ldo, labels, ch_b2 + (size_t)l*KCL, asg, cnt_i);

    scan_kernel<<<1, 256, 0, stream>>>(cnt_i, seg_st, cursor);

    scatter_kernel<<<NPTS/256, 256, 0, stream>>>(labels, asg, cursor, rowlist, seglist);

    means3_kernel<<<dim3(NPTS/64, DIM/256), 256, 0, stream>>>(
        feat, rowlist, seglist, sums);

    // refine: Y1 = meannorm(sums) @ ref_w1   (meannorm fused into staging)
    gemm64_kernel<<<dim3(NSEG/64, DIM/64), 256, 0, stream>>>(
        sums, r1hiT + (size_t)l*DIM*DIM, r1loT + (size_t)l*DIM*DIM, Y1, 1,
        cnt_i, off, nullptr, nullptr, nullptr, nullptr, nullptr);

    lnstats_kernel<<<NSEG, 256, 0, stream>>>(
        Y1, ref_b1 + (size_t)l*DIM, mS, rS);

    // Y2 = relu(LN(Y1+b1)*g+b) @ ref_w2     (LN-apply fused into staging)
    gemm64_kernel<<<dim3(NSEG/64, DIM/64), 256, 0, stream>>>(
        Y1, r2hiT + (size_t)l*DIM*DIM, r2loT + (size_t)l*DIM*DIM, Y2, 2,
        nullptr, nullptr, ref_b1 + (size_t)l*DIM,
        ln_g + (size_t)l*DIM, ln_b + (size_t)l*DIM, mS, rS);

    // lp + off update + next level's offW1b (fused); l=2 skips the offgemm part
    protoOffgemm_kernel<<<NCLS, 256, 0, stream>>>(
        Y2, ref_b2 + (size_t)l*DIM, cnt_i, off, lp_all + (size_t)l*NCLS*DIM,
        (l < NLVL-1) ? (ch_w1 + (size_t)(l+1)*DIM*HID) : nullptr,
        (l < NLVL-1) ? (ch_b1 + (size_t)(l+1)*HID) : nullptr,
        offW1b);
  }

  hipMemsetAsync(Hacc, 0, 2*NCLS*DIM*sizeof(float), stream);
  fgemm1_kernel<<<dim3(DIM/64, NLVL*DIM/128), 256, 0, stream>>>(lp_all, cw1, Hacc);
  fgemm2_kernel<<<dim3(DIM/64, DIM/128), 256, 0, stream>>>(Hacc, cb1, cw2, Oacc);
  fbias_kernel<<<NCLS*DIM/256, 256, 0, stream>>>(Oacc, cb2, out);
}

// Round 6
// 812.456 us; speedup vs baseline: 1.1534x; 1.1534x over previous
//
#include <hip/hip_runtime.h>

#define NPTS 65536
#define DIM  512
#define HID  256
#define KCL  16
#define NLVL 3
#define NCLS 64
#define NSEG (NCLS*KCL)
#define EPSF 1e-5f

typedef __bf16 bf16_t;
typedef bf16_t bf16x4 __attribute__((ext_vector_type(4)));
typedef bf16_t bf16x8 __attribute__((ext_vector_type(8)));
typedef float  f32x4  __attribute__((ext_vector_type(4)));

#define LDA 40   // padded LDS row stride in bf16 units
#define LDH2 68  // padded LDS row stride for f32 h-quarter tile (64 + 4 pad)

// ============================ W1 split+transpose (once): W1[l][k][j] -> [(l*256+j)][k] ====
__global__ __launch_bounds__(256) void wsplit_kernel(
    const float* __restrict__ w1, bf16_t* __restrict__ hiT, bf16_t* __restrict__ loT)
{
  int gid = blockIdx.x * 256 + threadIdx.x;   // 0..393215
  int n = gid >> 9, k = gid & 511;
  int l = n >> 8, j = n & 255;
  float v = w1[l*DIM*HID + k*HID + j];
  bf16_t h = (bf16_t)v;
  hiT[gid] = h;
  loT[gid] = (bf16_t)(v - (float)h);
}

// ============================ ref-W split+transpose, both weights in one launch ===========
__global__ __launch_bounds__(256) void wsplit2_kernel(
    const float* __restrict__ w1, const float* __restrict__ w2,
    bf16_t* __restrict__ h1, bf16_t* __restrict__ l1,
    bf16_t* __restrict__ h2, bf16_t* __restrict__ l2)
{
  const int per = NLVL*DIM*DIM;
  int gid = blockIdx.x * 256 + threadIdx.x;   // 0..2*per-1
  const float* w = (gid < per) ? w1 : w2;
  bf16_t* hh = (gid < per) ? h1 : h2;
  bf16_t* ll = (gid < per) ? l1 : l2;
  int g2 = (gid < per) ? gid : gid - per;
  int n512 = g2 >> 9, k = g2 & 511;
  int l = n512 >> 9, n = n512 & 511;
  float v = w[(size_t)l*DIM*DIM + (size_t)k*DIM + n];
  bf16_t h = (bf16_t)v;
  hh[g2] = h;
  ll[g2] = (bf16_t)(v - (float)h);
}

// ============================ cluster-head W2 split+transpose: [l][k][k2] -> [l][k2][k] ===
__global__ __launch_bounds__(256) void wsplitW2_kernel(
    const float* __restrict__ w2, bf16_t* __restrict__ hiT, bf16_t* __restrict__ loT)
{
  int gid = blockIdx.x * 256 + threadIdx.x;   // 0..NLVL*KCL*HID-1 = 12287
  int l = gid >> 12, rem = gid & 4095;
  int k2 = rem >> 8, k = rem & 255;
  float v = w2[(size_t)l*HID*KCL + k*KCL + k2];
  bf16_t h = (bf16_t)v;
  hiT[gid] = h;
  loT[gid] = (bf16_t)(v - (float)h);
}

// ============================ fused per-level GEMM + cluster assign (128x256, 8 waves) ====
// K-loop: acc = feat[128xK] @ W1[Kx256], 3-term hi/lo MFMA (gemm128-proven geometry).
// Epilogue: 4 col-quarter passes, DOUBLE-BUFFERED: while all waves MFMA quarter q from
//   one hS buffer, the owner waves of quarter q+1 write relu(acc+off) into the other.
//   logits[128x16] += h @ W2 (wave w owns rows w*16..w*16+16); width-16 shuffle argmax.
__global__ __launch_bounds__(512, 4) void gemmassign_kernel(
    const float* __restrict__ feat,
    const bf16_t* __restrict__ BhiT, const bf16_t* __restrict__ BloT,
    const bf16_t* __restrict__ w2hT, const bf16_t* __restrict__ w2lT,  // [KCL][HID]
    const float* __restrict__ offsrc, int ldo,
    const int* __restrict__ labels,
    const float* __restrict__ pb2,
    int* __restrict__ asg, int* __restrict__ cnt)
{
  // K-loop view: A(hi,lo) 128 rows + B(hi,lo) 256 rows, LDA-padded bf16 = 61440 B.
  // Epilogue view (overlay): 2x hS [128][LDH2] f32 = 69632 B. Max -> 69632 (2 blocks/CU).
  __shared__ __align__(16) unsigned char SMraw[2*128*LDH2*4];
  __shared__ int labs[128];
  bf16_t* SM  = (bf16_t*)SMraw;
  bf16_t* Ahi = SM;
  bf16_t* Alo = SM + 128*LDA;
  bf16_t* Bhi = SM + 256*LDA;
  bf16_t* Blo = SM + 512*LDA;

  const int t = threadIdx.x;
  const int row0 = blockIdx.x * 128;
  const int w = t >> 6, lane = t & 63;
  const int wm = w & 1, wn = w >> 1;
  const int fm = lane & 15, fq = lane >> 4;

  if (t < 128) labs[t] = labels[row0 + t];
  const float pv = pb2[fm];   // per-lane cluster bias (k2 = fm)

  f32x4 acc[4][4];
  #pragma unroll
  for (int i = 0; i < 4; i++)
    #pragma unroll
    for (int j = 0; j < 4; j++)
      #pragma unroll
      for (int r = 0; r < 4; r++) acc[i][j][r] = 0.f;

  for (int kc = 0; kc < DIM; kc += 32) {
    __syncthreads();
    // stage A: 128 rows x 32 k, f32 -> hi/lo bf16 (2 float4 per thread)
    #pragma unroll
    for (int p = 0; p < 2; p++) {
      int idx = t + 512*p;
      int r = idx >> 3, c = idx & 7;
      float4 v = *(const float4*)&feat[(size_t)(row0 + r)*DIM + kc + c*4];
      bf16x4 hi, lo;
      hi[0] = (bf16_t)v.x; lo[0] = (bf16_t)(v.x - (float)hi[0]);
      hi[1] = (bf16_t)v.y; lo[1] = (bf16_t)(v.y - (float)hi[1]);
      hi[2] = (bf16_t)v.z; lo[2] = (bf16_t)(v.z - (float)hi[2]);
      hi[3] = (bf16_t)v.w; lo[3] = (bf16_t)(v.w - (float)hi[3]);
      *(bf16x4*)&Ahi[r*LDA + c*4] = hi;
      *(bf16x4*)&Alo[r*LDA + c*4] = lo;
    }
    // stage B: 256 cols x 32 k, pre-split bf16 (2 bf16x8 per thread per array)
    #pragma unroll
    for (int p = 0; p < 2; p++) {
      int idx = t + 512*p;
      int n = idx >> 2, c = idx & 3;
      *(bf16x8*)&Bhi[n*LDA + c*8] = *(const bf16x8*)&BhiT[(size_t)n*DIM + kc + c*8];
      *(bf16x8*)&Blo[n*LDA + c*8] = *(const bf16x8*)&BloT[(size_t)n*DIM + kc + c*8];
    }
    __syncthreads();

    bf16x8 ah[4], al[4], bh[4], bl[4];
    #pragma unroll
    for (int mt = 0; mt < 4; mt++) {
      int rr = (wm*64 + mt*16 + fm)*LDA + fq*8;
      ah[mt] = *(bf16x8*)&Ahi[rr];
      al[mt] = *(bf16x8*)&Alo[rr];
    }
    #pragma unroll
    for (int nt = 0; nt < 4; nt++) {
      int rr = (wn*64 + nt*16 + fm)*LDA + fq*8;
      bh[nt] = *(bf16x8*)&Bhi[rr];
      bl[nt] = *(bf16x8*)&Blo[rr];
    }
    #pragma unroll
    for (int mt = 0; mt < 4; mt++)
      #pragma unroll
      for (int nt = 0; nt < 4; nt++) {
        acc[mt][nt] = __builtin_amdgcn_mfma_f32_16x16x32_bf16(ah[mt], bh[nt], acc[mt][nt], 0, 0, 0);
        acc[mt][nt] = __builtin_amdgcn_mfma_f32_16x16x32_bf16(ah[mt], bl[nt], acc[mt][nt], 0, 0, 0);
        acc[mt][nt] = __builtin_amdgcn_mfma_f32_16x16x32_bf16(al[mt], bh[nt], acc[mt][nt], 0, 0, 0);
      }
  }

  // ---------------- MFMA-based assign epilogue, double-buffered quarters ----------------
  __syncthreads();                       // all K-loop LDS reads done -> safe to overlay
  float* hA = (float*)SMraw;             // [128][LDH2] f32
  float* hB = hA + 128*LDH2;

  auto writeQ = [&](int q, float* buf) {
    #pragma unroll
    for (int nt = 0; nt < 4; nt++) {
      int colq = nt*16 + fm;
      int colg = q*64 + colq;
      #pragma unroll
      for (int mt = 0; mt < 4; mt++)
        #pragma unroll
        for (int r = 0; r < 4; r++) {
          int row = wm*64 + mt*16 + fq*4 + r;
          buf[row*LDH2 + colq] =
              fmaxf(acc[mt][nt][r] + offsrc[(size_t)labs[row]*ldo + colg], 0.f);
        }
    }
  };

  f32x4 lg = {0.f, 0.f, 0.f, 0.f};       // logits C-frag: row=w*16+fq*4+r, col(k2)=fm

  if (wn == 0) writeQ(0, hA);
  __syncthreads();
  #pragma unroll
  for (int q = 0; q < 4; q++) {
    float* cur = (q & 1) ? hB : hA;
    float* nxt = (q & 1) ? hA : hB;
    if (q < 3 && wn == q + 1) writeQ(q + 1, nxt);   // overlaps with MFMA below

    #pragma unroll
    for (int s = 0; s < 2; s++) {
      int kb = s*32 + fq*8;              // k within quarter
      f32x4 a0 = *(f32x4*)&cur[(w*16 + fm)*LDH2 + kb];
      f32x4 a1 = *(f32x4*)&cur[(w*16 + fm)*LDH2 + kb + 4];
      bf16x8 ahf, alf;
      #pragma unroll
      for (int j = 0; j < 4; j++) {
        bf16_t h0 = (bf16_t)a0[j]; ahf[j]   = h0; alf[j]   = (bf16_t)(a0[j] - (float)h0);
        bf16_t h1 = (bf16_t)a1[j]; ahf[4+j] = h1; alf[4+j] = (bf16_t)(a1[j] - (float)h1);
      }
      bf16x8 bhf = *(const bf16x8*)&w2hT[fm*HID + q*64 + kb];
      bf16x8 blf = *(const bf16x8*)&w2lT[fm*HID + q*64 + kb];
      lg = __builtin_amdgcn_mfma_f32_16x16x32_bf16(ahf, bhf, lg, 0, 0, 0);
      lg = __builtin_amdgcn_mfma_f32_16x16x32_bf16(ahf, blf, lg, 0, 0, 0);
      lg = __builtin_amdgcn_mfma_f32_16x16x32_bf16(alf, bhf, lg, 0, 0, 0);
    }
    if (q < 3) __syncthreads();
  }

  // argmax over k2 (= fm lanes), first-max tie-break, then scatter asg/cnt
  #pragma unroll
  for (int r = 0; r < 4; r++) {
    float v = lg[r] + pv;
    int idx = fm;
    #pragma unroll
    for (int ofs = 8; ofs > 0; ofs >>= 1) {
      float ov = __shfl_xor(v, ofs, 16);
      int   oi = __shfl_xor(idx, ofs, 16);
      if (ov > v || (ov == v && oi < idx)) { v = ov; idx = oi; }
    }
    if (fm == 0) {
      int rloc = w*16 + fq*4 + r;
      asg[row0 + rloc] = idx;
      atomicAdd(&cnt[labs[rloc]*KCL + idx], 1);
    }
  }
}

// ============================ refine GEMM: 64x64 tile, 4-term hi/lo, fused pre-ops ========
// mode 1: A[row][k] = (sums[row][k] + cnt[row]*off[cls][k]) / max(cnt,1)
//         epilogue: LN partial stats of (Y1+b1) -> atomicAdd mP[row], mP[NSEG+row]
// mode 2: A[row][k] = relu((Y1[row][k] + b1[k] - m) * rsqrt(var+eps) * g[k] + bb[k])
//         with m, var derived inline from mP (lnstats kernel eliminated)
__global__ __launch_bounds__(256) void gemm64_kernel(
    const float* __restrict__ Asrc,
    const bf16_t* __restrict__ BhiT, const bf16_t* __restrict__ BloT,
    float* __restrict__ C, int mode,
    const int* __restrict__ cnt, const float* __restrict__ off,
    const float* __restrict__ b1, const float* __restrict__ g,
    const float* __restrict__ bb, float* __restrict__ mP)
{
  __shared__ __align__(16) bf16_t Ahi[64*LDA];
  __shared__ __align__(16) bf16_t Alo[64*LDA];
  __shared__ __align__(16) bf16_t Bhi[64*LDA];
  __shared__ __align__(16) bf16_t Blo[64*LDA];
  __shared__ float rm[64], rr_[64];

  const int t = threadIdx.x;
  const int row0 = blockIdx.x * 64, col0 = blockIdx.y * 64;
  const int w = t >> 6, lane = t & 63;
  const int wm = w & 1, wn = w >> 1;
  const int fm = lane & 15, fq = lane >> 4;

  if (t < 64) {
    if (mode == 1) {
      int n = cnt[row0 + t];
      rm[t] = (float)n;
      rr_[t] = 1.f / fmaxf((float)n, 1.f);
    } else {
      float s1 = mP[row0 + t], s2 = mP[NSEG + row0 + t];
      float m = s1 * (1.f/512.f);
      float var = s2 * (1.f/512.f) - m*m;
      rm[t] = m;
      rr_[t] = rsqrtf(var + EPSF);
    }
  }

  f32x4 acc[2][2];
  #pragma unroll
  for (int i = 0; i < 2; i++)
    #pragma unroll
    for (int j = 0; j < 2; j++)
      #pragma unroll
      for (int r = 0; r < 4; r++) acc[i][j][r] = 0.f;

  for (int kc = 0; kc < DIM; kc += 32) {
    __syncthreads();
    #pragma unroll
    for (int p = 0; p < 2; p++) {
      int idx = t + 256*p;
      int r = idx >> 3, c = idx & 7;
      float4 v = *(const float4*)&Asrc[(size_t)(row0 + r)*DIM + kc + c*4];
      if (mode == 1) {
        int cls = (row0 + r) >> 4;
        float4 o = *(const float4*)&off[(size_t)cls*DIM + kc + c*4];
        float n = rm[r], inv = rr_[r];
        v.x = (v.x + n*o.x) * inv; v.y = (v.y + n*o.y) * inv;
        v.z = (v.z + n*o.z) * inv; v.w = (v.w + n*o.w) * inv;
      } else {
        float4 B1 = *(const float4*)&b1[kc + c*4];
        float4 G4 = *(const float4*)&g[kc + c*4];
        float4 BB = *(const float4*)&bb[kc + c*4];
        float m = rm[r], rs = rr_[r];
        v.x = fmaxf((v.x + B1.x - m)*rs*G4.x + BB.x, 0.f);
        v.y = fmaxf((v.y + B1.y - m)*rs*G4.y + BB.y, 0.f);
        v.z = fmaxf((v.z + B1.z - m)*rs*G4.z + BB.z, 0.f);
        v.w = fmaxf((v.w + B1.w - m)*rs*G4.w + BB.w, 0.f);
      }
      bf16x4 hi, lo;
      hi[0] = (bf16_t)v.x; lo[0] = (bf16_t)(v.x - (float)hi[0]);
      hi[1] = (bf16_t)v.y; lo[1] = (bf16_t)(v.y - (float)hi[1]);
      hi[2] = (bf16_t)v.z; lo[2] = (bf16_t)(v.z - (float)hi[2]);
      hi[3] = (bf16_t)v.w; lo[3] = (bf16_t)(v.w - (float)hi[3]);
      *(bf16x4*)&Ahi[r*LDA + c*4] = hi;
      *(bf16x4*)&Alo[r*LDA + c*4] = lo;
    }
    {
      int n = t >> 2, kof = (t & 3)*8;
      *(bf16x8*)&Bhi[n*LDA + kof] = *(const bf16x8*)&BhiT[(size_t)(col0 + n)*DIM + kc + kof];
      *(bf16x8*)&Blo[n*LDA + kof] = *(const bf16x8*)&BloT[(size_t)(col0 + n)*DIM + kc + kof];
    }
    __syncthreads();

    bf16x8 ah[2], al[2], bh[2], bl[2];
    #pragma unroll
    for (int mt = 0; mt < 2; mt++) {
      int idx = (wm*32 + mt*16 + fm)*LDA + fq*8;
      ah[mt] = *(bf16x8*)&Ahi[idx];
      al[mt] = *(bf16x8*)&Alo[idx];
    }
    #pragma unroll
    for (int nt = 0; nt < 2; nt++) {
      int idx = (wn*32 + nt*16 + fm)*LDA + fq*8;
      bh[nt] = *(bf16x8*)&Bhi[idx];
      bl[nt] = *(bf16x8*)&Blo[idx];
    }
    #pragma unroll
    for (int mt = 0; mt < 2; mt++)
      #pragma unroll
      for (int nt = 0; nt < 2; nt++) {
        acc[mt][nt] = __builtin_amdgcn_mfma_f32_16x16x32_bf16(ah[mt], bh[nt], acc[mt][nt], 0, 0, 0);
        acc[mt][nt] = __builtin_amdgcn_mfma_f32_16x16x32_bf16(ah[mt], bl[nt], acc[mt][nt], 0, 0, 0);
        acc[mt][nt] = __builtin_amdgcn_mfma_f32_16x16x32_bf16(al[mt], bh[nt], acc[mt][nt], 0, 0, 0);
        acc[mt][nt] = __builtin_amdgcn_mfma_f32_16x16x32_bf16(al[mt], bl[nt], acc[mt][nt], 0, 0, 0);
      }
  }

  #pragma unroll
  for (int mt = 0; mt < 2; mt++)
    #pragma unroll
    for (int nt = 0; nt < 2; nt++) {
      int col = col0 + wn*32 + nt*16 + fm;
      int rowb = row0 + wm*32 + mt*16 + fq*4;
      #pragma unroll
      for (int r = 0; r < 4; r++)
        C[(size_t)(rowb + r)*DIM + col] = acc[mt][nt][r];
    }

  // LN partial stats (mode 1 only): per-row sums of (Y1+b1) and (Y1+b1)^2 over this
  // block's 64 cols; 16-lane shuffle tree then one atomic pair per (row, wave).
  if (mode == 1) {
    float b1v[2];
    #pragma unroll
    for (int nt = 0; nt < 2; nt++) b1v[nt] = b1[col0 + wn*32 + nt*16 + fm];
    #pragma unroll
    for (int mt = 0; mt < 2; mt++)
      #pragma unroll
      for (int r = 0; r < 4; r++) {
        float c1 = 0.f, c2 = 0.f;
        #pragma unroll
        for (int nt = 0; nt < 2; nt++) {
          float v = acc[mt][nt][r] + b1v[nt];
          c1 += v; c2 += v*v;
        }
        #pragma unroll
        for (int ofs = 8; ofs > 0; ofs >>= 1) {
          c1 += __shfl_xor(c1, ofs, 16);
          c2 += __shfl_xor(c2, ofs, 16);
        }
        if (fm == 0) {
          int row = row0 + wm*32 + mt*16 + fq*4 + r;
          atomicAdd(&mP[row], c1);
          atomicAdd(&mP[NSEG + row], c2);
        }
      }
  }
}

// ============================ offW1b[c][j] = off[c]@W1_l[:,j] + b1[j] (l=0 handled by ldo=0)
// fused: lp[c] = mean over non-empty k of Y2 + b2; off += lp; then next-level offgemm.
__global__ __launch_bounds__(256) void protoOffgemm_kernel(
    const float* __restrict__ Y2, const float* __restrict__ b2,
    const int* __restrict__ cnt, float* __restrict__ off, float* __restrict__ lp_out,
    const float* __restrict__ w1next, const float* __restrict__ b1next,
    float* __restrict__ offW1b)
{
  __shared__ float offs[DIM];
  int c = blockIdx.x, t = threadIdx.x;
  int nes = 0;
  #pragma unroll
  for (int k = 0; k < KCL; k++) nes += (cnt[c*KCL + k] > 0);
  float inv = 1.f / (float)nes;
  #pragma unroll
  for (int h = 0; h < 2; h++) {
    int d = t + h*256;
    float s = 0.f;
    #pragma unroll
    for (int k = 0; k < KCL; k++)
      if (cnt[c*KCL + k] > 0) s += Y2[(size_t)(c*KCL + k)*DIM + d];
    float lp = s * inv + b2[d];
    lp_out[c*DIM + d] = lp;
    float on = off[c*DIM + d] + lp;
    off[c*DIM + d] = on;
    offs[d] = on;
  }
  if (w1next == nullptr) return;
  __syncthreads();
  // 4 independent accumulators to break the serial fmaf dependency chain
  float a0 = 0.f, a1 = 0.f, a2 = 0.f, a3 = 0.f;
  #pragma unroll 4
  for (int d = 0; d < DIM; d += 4) {
    a0 = fmaf(offs[d+0], w1next[(d+0)*HID + t], a0);
    a1 = fmaf(offs[d+1], w1next[(d+1)*HID + t], a1);
    a2 = fmaf(offs[d+2], w1next[(d+2)*HID + t], a2);
    a3 = fmaf(offs[d+3], w1next[(d+3)*HID + t], a3);
  }
  offW1b[c*HID + t] = ((a0 + a1) + (a2 + a3)) + b1next[t];
}

// ============================ exclusive scan (shuffle-based) ==============================
__global__ void scan_kernel(const int* __restrict__ cnt, int* __restrict__ seg_st,
                            int* __restrict__ cursor)
{
  int t = threadIdx.x;
  int4 v = *(const int4*)&cnt[t*4];
  int a0 = v.x, a1 = v.x + v.y, a2 = a1 + v.z, tot = a2 + v.w;
  int lane = t & 63, w = t >> 6;
  int sc = tot;
  #pragma unroll
  for (int ofs = 1; ofs < 64; ofs <<= 1) {
    int u = __shfl_up(sc, ofs);
    if (lane >= ofs) sc += u;
  }
  __shared__ int wt[4];
  if (lane == 63) wt[w] = sc;
  __syncthreads();
  int base = 0;
  #pragma unroll
  for (int i = 0; i < 4; i++) if (i < w) base += wt[i];
  int excl = base + sc - tot;
  seg_st[t*4 + 1] = excl + a0;
  seg_st[t*4 + 2] = excl + a1;
  seg_st[t*4 + 3] = excl + a2;
  seg_st[t*4 + 4] = excl + tot;
  if (t == 0) seg_st[0] = 0;
  int4 cur = {excl, excl + a0, excl + a1, excl + a2};
  *(int4*)&cursor[t*4] = cur;
}

// ============================ scatter rows into per-segment sorted lists ==================
__global__ __launch_bounds__(256) void scatter_kernel(
    const int* __restrict__ labels, const int* __restrict__ asg,
    int* __restrict__ cursor, int* __restrict__ rowlist, int* __restrict__ seglist)
{
  int i = blockIdx.x * 256 + threadIdx.x;
  int seg = labels[i]*KCL + asg[i];
  int pos = atomicAdd(&cursor[seg], 1);
  rowlist[pos] = i;
  seglist[pos] = seg;
}

// ============================ balanced segmented sums over sorted rowlist =================
__global__ __launch_bounds__(256) void means3_kernel(
    const float* __restrict__ feat, const int* __restrict__ rowlist,
    const int* __restrict__ seglist, float* __restrict__ sums)
{
  __shared__ int rows[64];
  __shared__ int segs[65];
  int t = threadIdx.x;
  int i0 = blockIdx.x * 64;
  int col = blockIdx.y * 256 + t;
  if (t < 64) { rows[t] = rowlist[i0 + t]; segs[t] = seglist[i0 + t]; }
  if (t == 64) segs[64] = -1;
  __syncthreads();
  float acc = 0.f;
  for (int base = 0; base < 64; base += 16) {
    float v[16];
    #pragma unroll
    for (int j = 0; j < 16; j++)
      v[j] = feat[(size_t)rows[base + j]*DIM + col];
    #pragma unroll
    for (int j = 0; j < 16; j++) {
      acc += v[j];
      if (segs[base + j] != segs[base + j + 1]) {
        atomicAdd(&sums[(size_t)segs[base + j]*DIM + col], acc);
        acc = 0.f;
      }
    }
  }
}

// ============================ final stage 1: Hacc += comb[64x1536] @ cw1 (K-split) ========
__global__ __launch_bounds__(256) void fgemm1_kernel(
    const float* __restrict__ lp_all, const float* __restrict__ cw1,
    float* __restrict__ Hacc)
{
  __shared__ float As[64*132];
  __shared__ float Ws[128*64];
  int t = threadIdx.x;
  int nc = blockIdx.x * 64, kc = blockIdx.y * 128;

  #pragma unroll
  for (int p = 0; p < 8; p++) {
    int i = t + 256*p;
    int m = i >> 5, k0 = (i & 31) << 2;
    int k = kc + k0;
    int l = k >> 9, d = k & 511;
    *(float4*)&As[m*132 + k0] = *(const float4*)&lp_all[(size_t)(l*NCLS + m)*DIM + d];
  }
  #pragma unroll
  for (int p = 0; p < 8; p++) {
    int i = t + 256*p;
    int k = i >> 4, n0 = (i & 15) << 2;
    *(float4*)&Ws[k*64 + n0] = *(const float4*)&cw1[(size_t)(kc + k)*DIM + nc + n0];
  }
  __syncthreads();

  int tn = (t & 15) * 4, tmg = (t >> 4) * 4;
  float acc[4][4];
  #pragma unroll
  for (int i = 0; i < 4; i++)
    #pragma unroll
    for (int j = 0; j < 4; j++) acc[i][j] = 0.f;

  for (int k = 0; k < 128; k += 4) {
    float4 a[4], w[4];
    #pragma unroll
    for (int i = 0; i < 4; i++) a[i] = *(float4*)&As[(tmg + i)*132 + k];
    #pragma unroll
    for (int j = 0; j < 4; j++) w[j] = *(float4*)&Ws[(k + j)*64 + tn];
    #pragma unroll
    for (int kk = 0; kk < 4; kk++) {
      float wv[4] = {w[kk].x, w[kk].y, w[kk].z, w[kk].w};
      float av[4] = {a[0][kk], a[1][kk], a[2][kk], a[3][kk]};
      #pragma unroll
      for (int i = 0; i < 4; i++)
        #pragma unroll
        for (int j = 0; j < 4; j++)
          acc[i][j] = fmaf(av[i], wv[j], acc[i][j]);
    }
  }
  #pragma unroll
  for (int i = 0; i < 4; i++)
    #pragma unroll
    for (int j = 0; j < 4; j++)
      atomicAdd(&Hacc[(size_t)(tmg + i)*DIM + nc + tn + j], acc[i][j]);
}

// ============================ final stage 2: Oacc += relu(Hacc+cb1) @ cw2 (K-split) =======
__global__ __launch_bounds__(256) void fgemm2_kernel(
    const float* __restrict__ Hacc, const float* __restrict__ cb1,
    const float* __restrict__ cw2, float* __restrict__ Oacc)
{
  __shared__ float As[64*132];
  __shared__ float Ws[128*64];
  int t = threadIdx.x;
  int nc = blockIdx.x * 64, kc = blockIdx.y * 128;

  #pragma unroll
  for (int p = 0; p < 8; p++) {
    int i = t + 256*p;
    int m = i >> 5, k0 = (i & 31) << 2;
    float4 v = *(const float4*)&Hacc[(size_t)m*DIM + kc + k0];
    float4 b = *(const float4*)&cb1[kc + k0];
    v.x = fmaxf(v.x + b.x, 0.f); v.y = fmaxf(v.y + b.y, 0.f);
    v.z = fmaxf(v.z + b.z, 0.f); v.w = fmaxf(v.w + b.w, 0.f);
    *(float4*)&As[m*132 + k0] = v;
  }
  #pragma unroll
  for (int p = 0; p < 8; p++) {
    int i = t + 256*p;
    int k = i >> 4, n0 = (i & 15) << 2;
    *(float4*)&Ws[k*64 + n0] = *(const float4*)&cw2[(size_t)(kc + k)*DIM + nc + n0];
  }
  __syncthreads();

  int tn = (t & 15) * 4, tmg = (t >> 4) * 4;
  float acc[4][4];
  #pragma unroll
  for (int i = 0; i < 4; i++)
    #pragma unroll
    for (int j = 0; j < 4; j++) acc[i][j] = 0.f;

  for (int k = 0; k < 128; k += 4) {
    float4 a[4], w[4];
    #pragma unroll
    for (int i = 0; i < 4; i++) a[i] = *(float4*)&As[(tmg + i)*132 + k];
    #pragma unroll
    for (int j = 0; j < 4; j++) w[j] = *(float4*)&Ws[(k + j)*64 + tn];
    #pragma unroll
    for (int kk = 0; kk < 4; kk++) {
      float wv[4] = {w[kk].x, w[kk].y, w[kk].z, w[kk].w};
      float av[4] = {a[0][kk], a[1][kk], a[2][kk], a[3][kk]};
      #pragma unroll
      for (int i = 0; i < 4; i++)
        #pragma unroll
        for (int j = 0; j < 4; j++)
          acc[i][j] = fmaf(av[i], wv[j], acc[i][j]);
    }
  }
  #pragma unroll
  for (int i = 0; i < 4; i++)
    #pragma unroll
    for (int j = 0; j < 4; j++)
      atomicAdd(&Oacc[(size_t)(tmg + i)*DIM + nc + tn + j], acc[i][j]);
}

// ============================ final stage 3: out = Oacc + cb2 =============================
__global__ __launch_bounds__(256) void fbias_kernel(
    const float* __restrict__ Oacc, const float* __restrict__ cb2,
    float* __restrict__ out)
{
  int gi = blockIdx.x * 256 + threadIdx.x;
  out[gi] = Oacc[gi] + cb2[gi & 511];
}

// ============================ launch ======================================================
extern "C" void kernel_launch(void* const* d_in, const int* in_sizes, int n_in,
                              void* d_out, int out_size, void* d_ws, size_t ws_size,
                              hipStream_t stream) {
  const float* feat   = (const float*)d_in[0];
  const int*   labels = (const int*)d_in[1];
  const float* ch_w1  = (const float*)d_in[2];
  const float* ch_b1  = (const float*)d_in[3];
  const float* ch_w2  = (const float*)d_in[4];
  const float* ch_b2  = (const float*)d_in[5];
  const float* ref_w1 = (const float*)d_in[6];
  const float* ref_b1 = (const float*)d_in[7];
  const float* ln_g   = (const float*)d_in[8];
  const float* ln_b   = (const float*)d_in[9];
  const float* ref_w2 = (const float*)d_in[10];
  const float* ref_b2 = (const float*)d_in[11];
  const float* cw1    = (const float*)d_in[12];
  const float* cb1    = (const float*)d_in[13];
  const float* cw2    = (const float*)d_in[14];
  const float* cb2    = (const float*)d_in[15];
  float* out = (float*)d_out;

  float* wsf = (float*)d_ws;
  float* off    = wsf;                    // 32768
  float* lp_all = off + 32768;            // 98304
  float* sums   = lp_all + 98304;         // NSEG*DIM = 524288
  int*   cnt_i  = (int*)(sums + 524288);  // NSEG (contiguous with sums+mP: one memset)
  float* mP     = (float*)(cnt_i + NSEG); // 2*NSEG (LN partial s1|s2)
  float* offW1b = mP + 2*NSEG;            // 16384
  float* Hacc   = offW1b + 16384;         // 32768
  float* Oacc   = Hacc + 32768;           // 32768
  float* Y1     = Oacc + 32768;           // 524288
  float* Y2     = Y1 + 524288;            // 524288

  bf16_t* whiT  = (bf16_t*)(Y2 + 524288);
  bf16_t* wloT  = whiT + (size_t)NLVL*HID*DIM;
  bf16_t* r1hiT = wloT + (size_t)NLVL*HID*DIM;
  bf16_t* r1loT = r1hiT + (size_t)NLVL*DIM*DIM;
  bf16_t* r2hiT = r1loT + (size_t)NLVL*DIM*DIM;
  bf16_t* r2loT = r2hiT + (size_t)NLVL*DIM*DIM;
  bf16_t* w2hT  = r2loT + (size_t)NLVL*DIM*DIM;     // [NLVL][KCL][HID]
  bf16_t* w2lT  = w2hT + (size_t)NLVL*KCL*HID;
  int* asg     = (int*)(w2lT + (size_t)NLVL*KCL*HID);
  int* rowlist = asg + NPTS;
  int* seglist = rowlist + NPTS;
  int* seg_st  = seglist + NPTS;       // 1025 used, 1040 reserved
  int* cursor  = seg_st + 1040;        // NSEG

  hipMemsetAsync(off, 0, NCLS*DIM*sizeof(float), stream);

  wsplit_kernel<<<NLVL*HID*DIM/256, 256, 0, stream>>>(ch_w1, whiT, wloT);
  wsplit2_kernel<<<2*NLVL*DIM*DIM/256, 256, 0, stream>>>(
      ref_w1, ref_w2, r1hiT, r1loT, r2hiT, r2loT);
  wsplitW2_kernel<<<NLVL*KCL*HID/256, 256, 0, stream>>>(ch_w2, w2hT, w2lT);

  for (int l = 0; l < NLVL; l++) {
    // zero sums + cnt + mP in one shot (contiguous)
    hipMemsetAsync(sums, 0, (NSEG*DIM + NSEG + 2*NSEG)*sizeof(float), stream);

    // l=0: off==0 -> offW1b[c] == b1 for all c -> read b1 with row-stride 0
    const float* offsrc = (l == 0) ? ch_b1 : offW1b;
    int ldo = (l == 0) ? 0 : HID;

    // fused GEMM (feat @ W1_l, 3-term hi/lo) + dbuf MFMA assign epilogue -> asg, cnt
    gemmassign_kernel<<<NPTS/128, 512, 0, stream>>>(
        feat, whiT + (size_t)l*HID*DIM, wloT + (size_t)l*HID*DIM,
        w2hT + (size_t)l*KCL*HID, w2lT + (size_t)l*KCL*HID,
        offsrc, ldo, labels,
        ch_b2 + (size_t)l*KCL,
        asg, cnt_i);

    scan_kernel<<<1, 256, 0, stream>>>(cnt_i, seg_st, cursor);

    scatter_kernel<<<NPTS/256, 256, 0, stream>>>(labels, asg, cursor, rowlist, seglist);

    means3_kernel<<<dim3(NPTS/64, DIM/256), 256, 0, stream>>>(
        feat, rowlist, seglist, sums);

    // refine: Y1 = meannorm(sums) @ ref_w1 ; epilogue accumulates LN stats into mP
    gemm64_kernel<<<dim3(NSEG/64, DIM/64), 256, 0, stream>>>(
        sums, r1hiT + (size_t)l*DIM*DIM, r1loT + (size_t)l*DIM*DIM, Y1, 1,
        cnt_i, off, ref_b1 + (size_t)l*DIM, nullptr, nullptr, mP);

    // Y2 = relu(LN(Y1+b1)*g+b) @ ref_w2   (LN stats derived from mP inline)
    gemm64_kernel<<<dim3(NSEG/64, DIM/64), 256, 0, stream>>>(
        Y1, r2hiT + (size_t)l*DIM*DIM, r2loT + (size_t)l*DIM*DIM, Y2, 2,
        nullptr, nullptr, ref_b1 + (size_t)l*DIM,
        ln_g + (size_t)l*DIM, ln_b + (size_t)l*DIM, mP);

    // lp + off update + next level's offW1b (fused); l=2 skips the offgemm part
    protoOffgemm_kernel<<<NCLS, 256, 0, stream>>>(
        Y2, ref_b2 + (size_t)l*DIM, cnt_i, off, lp_all + (size_t)l*NCLS*DIM,
        (l < NLVL-1) ? (ch_w1 + (size_t)(l+1)*DIM*HID) : nullptr,
        (l < NLVL-1) ? (ch_b1 + (size_t)(l+1)*HID) : nullptr,
        offW1b);
  }

  hipMemsetAsync(Hacc, 0, 2*NCLS*DIM*sizeof(float), stream);
  fgemm1_kernel<<<dim3(DIM/64, NLVL*DIM/128), 256, 0, stream>>>(lp_all, cw1, Hacc);
  fgemm2_kernel<<<dim3(DIM/64, DIM/128), 256, 0, stream>>>(Hacc, cb1, cw2, Oacc);
  fbias_kernel<<<NCLS*DIM/256, 256, 0, stream>>>(Oacc, cb2, out);
}

// Round 7
// 783.706 us; speedup vs baseline: 1.1957x; 1.0367x over previous
//
#include <hip/hip_runtime.h>

#define NPTS 65536
#define DIM  512
#define HID  256
#define KCL  16
#define NLVL 3
#define NCLS 64
#define NSEG (NCLS*KCL)
#define EPSF 1e-5f

typedef __bf16 bf16_t;
typedef bf16_t bf16x4 __attribute__((ext_vector_type(4)));
typedef bf16_t bf16x8 __attribute__((ext_vector_type(8)));
typedef float  f32x4  __attribute__((ext_vector_type(4)));

#define LDA 40   // padded LDS row stride in bf16 units
#define LDH2 68  // padded LDS row stride for f32 h-quarter tile (64 + 4 pad)

// ============================ W1 split+transpose (once): W1[l][k][j] -> [(l*256+j)][k] ====
__global__ __launch_bounds__(256) void wsplit_kernel(
    const float* __restrict__ w1, bf16_t* __restrict__ hiT, bf16_t* __restrict__ loT)
{
  int gid = blockIdx.x * 256 + threadIdx.x;   // 0..393215
  int n = gid >> 9, k = gid & 511;
  int l = n >> 8, j = n & 255;
  float v = w1[l*DIM*HID + k*HID + j];
  bf16_t h = (bf16_t)v;
  hiT[gid] = h;
  loT[gid] = (bf16_t)(v - (float)h);
}

// ============================ ref-W split+transpose, both weights in one launch ===========
__global__ __launch_bounds__(256) void wsplit2_kernel(
    const float* __restrict__ w1, const float* __restrict__ w2,
    bf16_t* __restrict__ h1, bf16_t* __restrict__ l1,
    bf16_t* __restrict__ h2, bf16_t* __restrict__ l2)
{
  const int per = NLVL*DIM*DIM;
  int gid = blockIdx.x * 256 + threadIdx.x;   // 0..2*per-1
  const float* w = (gid < per) ? w1 : w2;
  bf16_t* hh = (gid < per) ? h1 : h2;
  bf16_t* ll = (gid < per) ? l1 : l2;
  int g2 = (gid < per) ? gid : gid - per;
  int n512 = g2 >> 9, k = g2 & 511;
  int l = n512 >> 9, n = n512 & 511;
  float v = w[(size_t)l*DIM*DIM + (size_t)k*DIM + n];
  bf16_t h = (bf16_t)v;
  hh[g2] = h;
  ll[g2] = (bf16_t)(v - (float)h);
}

// ============================ cluster-head W2 split+transpose: [l][k][k2] -> [l][k2][k] ===
__global__ __launch_bounds__(256) void wsplitW2_kernel(
    const float* __restrict__ w2, bf16_t* __restrict__ hiT, bf16_t* __restrict__ loT)
{
  int gid = blockIdx.x * 256 + threadIdx.x;   // 0..NLVL*KCL*HID-1 = 12287
  int l = gid >> 12, rem = gid & 4095;
  int k2 = rem >> 8, k = rem & 255;
  float v = w2[(size_t)l*HID*KCL + k*KCL + k2];
  bf16_t h = (bf16_t)v;
  hiT[gid] = h;
  loT[gid] = (bf16_t)(v - (float)h);
}

// ============================ fused per-level GEMM + cluster assign (128x256, 8 waves) ====
// K-loop: acc = feat[128xK] @ W1[Kx256], 3-term hi/lo MFMA (gemm128-proven geometry).
// Epilogue (R4-proven single-buffer): 4 col-quarter passes: h=relu(acc+off) -> LDS f32;
//   logits[128x16] += h @ W2 via 3-term hi/lo MFMA (wave w owns rows w*16..w*16+16);
//   argmax over k2 via width-16 shuffle, first-max tie-break.
__global__ __launch_bounds__(512, 4) void gemmassign_kernel(
    const float* __restrict__ feat,
    const bf16_t* __restrict__ BhiT, const bf16_t* __restrict__ BloT,
    const bf16_t* __restrict__ w2hT, const bf16_t* __restrict__ w2lT,  // [KCL][HID]
    const float* __restrict__ offsrc, int ldo,
    const int* __restrict__ labels,
    const float* __restrict__ pb2,
    int* __restrict__ asg, int* __restrict__ cnt)
{
  // K-loop view: A(hi,lo) 128 rows + B(hi,lo) 256 rows, LDA-padded bf16 = 61440 B.
  // Epilogue view (overlay): hS [128][LDH2] f32 = 34816 B.
  __shared__ __align__(16) unsigned char SMraw[768*LDA*2];
  __shared__ int labs[128];
  bf16_t* SM  = (bf16_t*)SMraw;
  bf16_t* Ahi = SM;
  bf16_t* Alo = SM + 128*LDA;
  bf16_t* Bhi = SM + 256*LDA;
  bf16_t* Blo = SM + 512*LDA;

  const int t = threadIdx.x;
  const int row0 = blockIdx.x * 128;
  const int w = t >> 6, lane = t & 63;
  const int wm = w & 1, wn = w >> 1;
  const int fm = lane & 15, fq = lane >> 4;

  if (t < 128) labs[t] = labels[row0 + t];
  const float pv = pb2[fm];   // per-lane cluster bias (k2 = fm)

  f32x4 acc[4][4];
  #pragma unroll
  for (int i = 0; i < 4; i++)
    #pragma unroll
    for (int j = 0; j < 4; j++)
      #pragma unroll
      for (int r = 0; r < 4; r++) acc[i][j][r] = 0.f;

  for (int kc = 0; kc < DIM; kc += 32) {
    __syncthreads();
    // stage A: 128 rows x 32 k, f32 -> hi/lo bf16 (2 float4 per thread)
    #pragma unroll
    for (int p = 0; p < 2; p++) {
      int idx = t + 512*p;
      int r = idx >> 3, c = idx & 7;
      float4 v = *(const float4*)&feat[(size_t)(row0 + r)*DIM + kc + c*4];
      bf16x4 hi, lo;
      hi[0] = (bf16_t)v.x; lo[0] = (bf16_t)(v.x - (float)hi[0]);
      hi[1] = (bf16_t)v.y; lo[1] = (bf16_t)(v.y - (float)hi[1]);
      hi[2] = (bf16_t)v.z; lo[2] = (bf16_t)(v.z - (float)hi[2]);
      hi[3] = (bf16_t)v.w; lo[3] = (bf16_t)(v.w - (float)hi[3]);
      *(bf16x4*)&Ahi[r*LDA + c*4] = hi;
      *(bf16x4*)&Alo[r*LDA + c*4] = lo;
    }
    // stage B: 256 cols x 32 k, pre-split bf16 (2 bf16x8 per thread per array)
    #pragma unroll
    for (int p = 0; p < 2; p++) {
      int idx = t + 512*p;
      int n = idx >> 2, c = idx & 3;
      *(bf16x8*)&Bhi[n*LDA + c*8] = *(const bf16x8*)&BhiT[(size_t)n*DIM + kc + c*8];
      *(bf16x8*)&Blo[n*LDA + c*8] = *(const bf16x8*)&BloT[(size_t)n*DIM + kc + c*8];
    }
    __syncthreads();

    bf16x8 ah[4], al[4], bh[4], bl[4];
    #pragma unroll
    for (int mt = 0; mt < 4; mt++) {
      int rr = (wm*64 + mt*16 + fm)*LDA + fq*8;
      ah[mt] = *(bf16x8*)&Ahi[rr];
      al[mt] = *(bf16x8*)&Alo[rr];
    }
    #pragma unroll
    for (int nt = 0; nt < 4; nt++) {
      int rr = (wn*64 + nt*16 + fm)*LDA + fq*8;
      bh[nt] = *(bf16x8*)&Bhi[rr];
      bl[nt] = *(bf16x8*)&Blo[rr];
    }
    #pragma unroll
    for (int mt = 0; mt < 4; mt++)
      #pragma unroll
      for (int nt = 0; nt < 4; nt++) {
        acc[mt][nt] = __builtin_amdgcn_mfma_f32_16x16x32_bf16(ah[mt], bh[nt], acc[mt][nt], 0, 0, 0);
        acc[mt][nt] = __builtin_amdgcn_mfma_f32_16x16x32_bf16(ah[mt], bl[nt], acc[mt][nt], 0, 0, 0);
        acc[mt][nt] = __builtin_amdgcn_mfma_f32_16x16x32_bf16(al[mt], bh[nt], acc[mt][nt], 0, 0, 0);
      }
  }

  // ---------------- MFMA-based assign epilogue (4 col-quarter passes) ----------------
  __syncthreads();                       // all LDS tile reads done -> safe to overlay
  float* hS = (float*)SMraw;             // [128][LDH2] f32

  f32x4 lg = {0.f, 0.f, 0.f, 0.f};       // logits C-frag: row=w*16+fq*4+r, col(k2)=fm

  #pragma unroll
  for (int q = 0; q < 4; q++) {
    // write phase: the 2 waves with wn==q own cols [q*64, q*64+64)
    if (wn == q) {
      #pragma unroll
      for (int nt = 0; nt < 4; nt++) {
        int colq = nt*16 + fm;           // col within quarter
        int colg = q*64 + colq;          // global hidden col
        #pragma unroll
        for (int mt = 0; mt < 4; mt++)
          #pragma unroll
          for (int r = 0; r < 4; r++) {
            int row = wm*64 + mt*16 + fq*4 + r;
            float hv = fmaxf(acc[mt][nt][r] +
                             offsrc[(size_t)labs[row]*ldo + colg], 0.f);
            hS[row*LDH2 + colq] = hv;
          }
      }
    }
    __syncthreads();

    // MFMA phase: wave w -> logits rows [w*16, w*16+16) over this quarter's 64 k-cols
    #pragma unroll
    for (int s = 0; s < 2; s++) {
      int kb = s*32 + fq*8;              // k within quarter
      f32x4 a0 = *(f32x4*)&hS[(w*16 + fm)*LDH2 + kb];
      f32x4 a1 = *(f32x4*)&hS[(w*16 + fm)*LDH2 + kb + 4];
      bf16x8 ahf, alf;
      #pragma unroll
      for (int j = 0; j < 4; j++) {
        bf16_t h0 = (bf16_t)a0[j]; ahf[j]   = h0; alf[j]   = (bf16_t)(a0[j] - (float)h0);
        bf16_t h1 = (bf16_t)a1[j]; ahf[4+j] = h1; alf[4+j] = (bf16_t)(a1[j] - (float)h1);
      }
      bf16x8 bhf = *(const bf16x8*)&w2hT[fm*HID + q*64 + kb];
      bf16x8 blf = *(const bf16x8*)&w2lT[fm*HID + q*64 + kb];
      lg = __builtin_amdgcn_mfma_f32_16x16x32_bf16(ahf, bhf, lg, 0, 0, 0);
      lg = __builtin_amdgcn_mfma_f32_16x16x32_bf16(ahf, blf, lg, 0, 0, 0);
      lg = __builtin_amdgcn_mfma_f32_16x16x32_bf16(alf, bhf, lg, 0, 0, 0);
    }
    __syncthreads();                     // reads done before next quarter's writes
  }

  // argmax over k2 (= fm lanes), first-max tie-break, then scatter asg/cnt
  #pragma unroll
  for (int r = 0; r < 4; r++) {
    float v = lg[r] + pv;
    int idx = fm;
    #pragma unroll
    for (int ofs = 8; ofs > 0; ofs >>= 1) {
      float ov = __shfl_xor(v, ofs, 16);
      int   oi = __shfl_xor(idx, ofs, 16);
      if (ov > v || (ov == v && oi < idx)) { v = ov; idx = oi; }
    }
    if (fm == 0) {
      int rloc = w*16 + fq*4 + r;
      asg[row0 + rloc] = idx;
      atomicAdd(&cnt[labs[rloc]*KCL + idx], 1);
    }
  }
}

// ============================ refine GEMM: 64x64 tile, 4-term hi/lo, fused pre-ops ========
// mode 1: A[row][k] = (sums[row][k] + cnt[row]*off[cls][k]) / max(cnt,1)
//         epilogue: LN partial stats of (Y1+b1) -> atomicAdd mP[row], mP[NSEG+row]
//         grid (16,8,1), plain C store.
// mode 2: A[row][k] = relu((Y1[row][k] + b1[k] - m) * rsqrt(var+eps) * g[k] + bb[k])
//         grid (16,8,2): K-split over z (K=256 each), atomicAdd into pre-zeroed C.
__global__ __launch_bounds__(256) void gemm64_kernel(
    const float* __restrict__ Asrc,
    const bf16_t* __restrict__ BhiT, const bf16_t* __restrict__ BloT,
    float* __restrict__ C, int mode,
    const int* __restrict__ cnt, const float* __restrict__ off,
    const float* __restrict__ b1, const float* __restrict__ g,
    const float* __restrict__ bb, float* __restrict__ mP)
{
  __shared__ __align__(16) bf16_t Ahi[64*LDA];
  __shared__ __align__(16) bf16_t Alo[64*LDA];
  __shared__ __align__(16) bf16_t Bhi[64*LDA];
  __shared__ __align__(16) bf16_t Blo[64*LDA];
  __shared__ float rm[64], rr_[64];

  const int t = threadIdx.x;
  const int row0 = blockIdx.x * 64, col0 = blockIdx.y * 64;
  const int w = t >> 6, lane = t & 63;
  const int wm = w & 1, wn = w >> 1;
  const int fm = lane & 15, fq = lane >> 4;

  if (t < 64) {
    if (mode == 1) {
      int n = cnt[row0 + t];
      rm[t] = (float)n;
      rr_[t] = 1.f / fmaxf((float)n, 1.f);
    } else {
      float s1 = mP[row0 + t], s2 = mP[NSEG + row0 + t];
      float m = s1 * (1.f/512.f);
      float var = s2 * (1.f/512.f) - m*m;
      rm[t] = m;
      rr_[t] = rsqrtf(var + EPSF);
    }
  }

  f32x4 acc[2][2];
  #pragma unroll
  for (int i = 0; i < 2; i++)
    #pragma unroll
    for (int j = 0; j < 2; j++)
      #pragma unroll
      for (int r = 0; r < 4; r++) acc[i][j][r] = 0.f;

  const int kstart = (mode == 2) ? blockIdx.z * 256 : 0;
  const int kend   = (mode == 2) ? kstart + 256 : DIM;

  for (int kc = kstart; kc < kend; kc += 32) {
    __syncthreads();
    #pragma unroll
    for (int p = 0; p < 2; p++) {
      int idx = t + 256*p;
      int r = idx >> 3, c = idx & 7;
      float4 v = *(const float4*)&Asrc[(size_t)(row0 + r)*DIM + kc + c*4];
      if (mode == 1) {
        int cls = (row0 + r) >> 4;
        float4 o = *(const float4*)&off[(size_t)cls*DIM + kc + c*4];
        float n = rm[r], inv = rr_[r];
        v.x = (v.x + n*o.x) * inv; v.y = (v.y + n*o.y) * inv;
        v.z = (v.z + n*o.z) * inv; v.w = (v.w + n*o.w) * inv;
      } else {
        float4 B1 = *(const float4*)&b1[kc + c*4];
        float4 G4 = *(const float4*)&g[kc + c*4];
        float4 BB = *(const float4*)&bb[kc + c*4];
        float m = rm[r], rs = rr_[r];
        v.x = fmaxf((v.x + B1.x - m)*rs*G4.x + BB.x, 0.f);
        v.y = fmaxf((v.y + B1.y - m)*rs*G4.y + BB.y, 0.f);
        v.z = fmaxf((v.z + B1.z - m)*rs*G4.z + BB.z, 0.f);
        v.w = fmaxf((v.w + B1.w - m)*rs*G4.w + BB.w, 0.f);
      }
      bf16x4 hi, lo;
      hi[0] = (bf16_t)v.x; lo[0] = (bf16_t)(v.x - (float)hi[0]);
      hi[1] = (bf16_t)v.y; lo[1] = (bf16_t)(v.y - (float)hi[1]);
      hi[2] = (bf16_t)v.z; lo[2] = (bf16_t)(v.z - (float)hi[2]);
      hi[3] = (bf16_t)v.w; lo[3] = (bf16_t)(v.w - (float)hi[3]);
      *(bf16x4*)&Ahi[r*LDA + c*4] = hi;
      *(bf16x4*)&Alo[r*LDA + c*4] = lo;
    }
    {
      int n = t >> 2, kof = (t & 3)*8;
      *(bf16x8*)&Bhi[n*LDA + kof] = *(const bf16x8*)&BhiT[(size_t)(col0 + n)*DIM + kc + kof];
      *(bf16x8*)&Blo[n*LDA + kof] = *(const bf16x8*)&BloT[(size_t)(col0 + n)*DIM + kc + kof];
    }
    __syncthreads();

    bf16x8 ah[2], al[2], bh[2], bl[2];
    #pragma unroll
    for (int mt = 0; mt < 2; mt++) {
      int idx = (wm*32 + mt*16 + fm)*LDA + fq*8;
      ah[mt] = *(bf16x8*)&Ahi[idx];
      al[mt] = *(bf16x8*)&Alo[idx];
    }
    #pragma unroll
    for (int nt = 0; nt < 2; nt++) {
      int idx = (wn*32 + nt*16 + fm)*LDA + fq*8;
      bh[nt] = *(bf16x8*)&Bhi[idx];
      bl[nt] = *(bf16x8*)&Blo[idx];
    }
    #pragma unroll
    for (int mt = 0; mt < 2; mt++)
      #pragma unroll
      for (int nt = 0; nt < 2; nt++) {
        acc[mt][nt] = __builtin_amdgcn_mfma_f32_16x16x32_bf16(ah[mt], bh[nt], acc[mt][nt], 0, 0, 0);
        acc[mt][nt] = __builtin_amdgcn_mfma_f32_16x16x32_bf16(ah[mt], bl[nt], acc[mt][nt], 0, 0, 0);
        acc[mt][nt] = __builtin_amdgcn_mfma_f32_16x16x32_bf16(al[mt], bh[nt], acc[mt][nt], 0, 0, 0);
        acc[mt][nt] = __builtin_amdgcn_mfma_f32_16x16x32_bf16(al[mt], bl[nt], acc[mt][nt], 0, 0, 0);
      }
  }

  #pragma unroll
  for (int mt = 0; mt < 2; mt++)
    #pragma unroll
    for (int nt = 0; nt < 2; nt++) {
      int col = col0 + wn*32 + nt*16 + fm;
      int rowb = row0 + wm*32 + mt*16 + fq*4;
      #pragma unroll
      for (int r = 0; r < 4; r++) {
        if (mode == 2)
          atomicAdd(&C[(size_t)(rowb + r)*DIM + col], acc[mt][nt][r]);
        else
          C[(size_t)(rowb + r)*DIM + col] = acc[mt][nt][r];
      }
    }

  // LN partial stats (mode 1 only): per-row sums of (Y1+b1) and (Y1+b1)^2 over this
  // block's 64 cols; 16-lane shuffle tree then one atomic pair per (row, wave).
  if (mode == 1) {
    float b1v[2];
    #pragma unroll
    for (int nt = 0; nt < 2; nt++) b1v[nt] = b1[col0 + wn*32 + nt*16 + fm];
    #pragma unroll
    for (int mt = 0; mt < 2; mt++)
      #pragma unroll
      for (int r = 0; r < 4; r++) {
        float c1 = 0.f, c2 = 0.f;
        #pragma unroll
        for (int nt = 0; nt < 2; nt++) {
          float v = acc[mt][nt][r] + b1v[nt];
          c1 += v; c2 += v*v;
        }
        #pragma unroll
        for (int ofs = 8; ofs > 0; ofs >>= 1) {
          c1 += __shfl_xor(c1, ofs, 16);
          c2 += __shfl_xor(c2, ofs, 16);
        }
        if (fm == 0) {
          int row = row0 + wm*32 + mt*16 + fq*4 + r;
          atomicAdd(&mP[row], c1);
          atomicAdd(&mP[NSEG + row], c2);
        }
      }
  }
}

// ============================ offW1b[c][j] = off[c]@W1_l[:,j] + b1[j] (l=0 handled by ldo=0)
// fused: lp[c] = mean over non-empty k of Y2 + b2; off += lp; then next-level offgemm.
__global__ __launch_bounds__(256) void protoOffgemm_kernel(
    const float* __restrict__ Y2, const float* __restrict__ b2,
    const int* __restrict__ cnt, float* __restrict__ off, float* __restrict__ lp_out,
    const float* __restrict__ w1next, const float* __restrict__ b1next,
    float* __restrict__ offW1b)
{
  __shared__ float offs[DIM];
  int c = blockIdx.x, t = threadIdx.x;
  int nes = 0;
  #pragma unroll
  for (int k = 0; k < KCL; k++) nes += (cnt[c*KCL + k] > 0);
  float inv = 1.f / (float)nes;
  #pragma unroll
  for (int h = 0; h < 2; h++) {
    int d = t + h*256;
    float s = 0.f;
    #pragma unroll
    for (int k = 0; k < KCL; k++)
      if (cnt[c*KCL + k] > 0) s += Y2[(size_t)(c*KCL + k)*DIM + d];
    float lp = s * inv + b2[d];
    lp_out[c*DIM + d] = lp;
    float on = off[c*DIM + d] + lp;
    off[c*DIM + d] = on;
    offs[d] = on;
  }
  if (w1next == nullptr) return;
  __syncthreads();
  // 4 independent accumulators to break the serial fmaf dependency chain
  float a0 = 0.f, a1 = 0.f, a2 = 0.f, a3 = 0.f;
  #pragma unroll 4
  for (int d = 0; d < DIM; d += 4) {
    a0 = fmaf(offs[d+0], w1next[(d+0)*HID + t], a0);
    a1 = fmaf(offs[d+1], w1next[(d+1)*HID + t], a1);
    a2 = fmaf(offs[d+2], w1next[(d+2)*HID + t], a2);
    a3 = fmaf(offs[d+3], w1next[(d+3)*HID + t], a3);
  }
  offW1b[c*HID + t] = ((a0 + a1) + (a2 + a3)) + b1next[t];
}

// ============================ exclusive scan (shuffle-based) ==============================
__global__ void scan_kernel(const int* __restrict__ cnt, int* __restrict__ seg_st,
                            int* __restrict__ cursor)
{
  int t = threadIdx.x;
  int4 v = *(const int4*)&cnt[t*4];
  int a0 = v.x, a1 = v.x + v.y, a2 = a1 + v.z, tot = a2 + v.w;
  int lane = t & 63, w = t >> 6;
  int sc = tot;
  #pragma unroll
  for (int ofs = 1; ofs < 64; ofs <<= 1) {
    int u = __shfl_up(sc, ofs);
    if (lane >= ofs) sc += u;
  }
  __shared__ int wt[4];
  if (lane == 63) wt[w] = sc;
  __syncthreads();
  int base = 0;
  #pragma unroll
  for (int i = 0; i < 4; i++) if (i < w) base += wt[i];
  int excl = base + sc - tot;
  seg_st[t*4 + 1] = excl + a0;
  seg_st[t*4 + 2] = excl + a1;
  seg_st[t*4 + 3] = excl + a2;
  seg_st[t*4 + 4] = excl + tot;
  if (t == 0) seg_st[0] = 0;
  int4 cur = {excl, excl + a0, excl + a1, excl + a2};
  *(int4*)&cursor[t*4] = cur;
}

// ============================ scatter rows into per-segment sorted lists ==================
__global__ __launch_bounds__(256) void scatter_kernel(
    const int* __restrict__ labels, const int* __restrict__ asg,
    int* __restrict__ cursor, int* __restrict__ rowlist, int* __restrict__ seglist)
{
  int i = blockIdx.x * 256 + threadIdx.x;
  int seg = labels[i]*KCL + asg[i];
  int pos = atomicAdd(&cursor[seg], 1);
  rowlist[pos] = i;
  seglist[pos] = seg;
}

// ============================ balanced segmented sums over sorted rowlist =================
__global__ __launch_bounds__(256) void means3_kernel(
    const float* __restrict__ feat, const int* __restrict__ rowlist,
    const int* __restrict__ seglist, float* __restrict__ sums)
{
  __shared__ int rows[64];
  __shared__ int segs[65];
  int t = threadIdx.x;
  int i0 = blockIdx.x * 64;
  int col = blockIdx.y * 256 + t;
  if (t < 64) { rows[t] = rowlist[i0 + t]; segs[t] = seglist[i0 + t]; }
  if (t == 64) segs[64] = -1;
  __syncthreads();
  float acc = 0.f;
  for (int base = 0; base < 64; base += 16) {
    float v[16];
    #pragma unroll
    for (int j = 0; j < 16; j++)
      v[j] = feat[(size_t)rows[base + j]*DIM + col];
    #pragma unroll
    for (int j = 0; j < 16; j++) {
      acc += v[j];
      if (segs[base + j] != segs[base + j + 1]) {
        atomicAdd(&sums[(size_t)segs[base + j]*DIM + col], acc);
        acc = 0.f;
      }
    }
  }
}

// ============================ final stage 1: Hacc += comb[64x1536] @ cw1 (K-split) ========
__global__ __launch_bounds__(256) void fgemm1_kernel(
    const float* __restrict__ lp_all, const float* __restrict__ cw1,
    float* __restrict__ Hacc)
{
  __shared__ float As[64*132];
  __shared__ float Ws[128*64];
  int t = threadIdx.x;
  int nc = blockIdx.x * 64, kc = blockIdx.y * 128;

  #pragma unroll
  for (int p = 0; p < 8; p++) {
    int i = t + 256*p;
    int m = i >> 5, k0 = (i & 31) << 2;
    int k = kc + k0;
    int l = k >> 9, d = k & 511;
    *(float4*)&As[m*132 + k0] = *(const float4*)&lp_all[(size_t)(l*NCLS + m)*DIM + d];
  }
  #pragma unroll
  for (int p = 0; p < 8; p++) {
    int i = t + 256*p;
    int k = i >> 4, n0 = (i & 15) << 2;
    *(float4*)&Ws[k*64 + n0] = *(const float4*)&cw1[(size_t)(kc + k)*DIM + nc + n0];
  }
  __syncthreads();

  int tn = (t & 15) * 4, tmg = (t >> 4) * 4;
  float acc[4][4];
  #pragma unroll
  for (int i = 0; i < 4; i++)
    #pragma unroll
    for (int j = 0; j < 4; j++) acc[i][j] = 0.f;

  for (int k = 0; k < 128; k += 4) {
    float4 a[4], w[4];
    #pragma unroll
    for (int i = 0; i < 4; i++) a[i] = *(float4*)&As[(tmg + i)*132 + k];
    #pragma unroll
    for (int j = 0; j < 4; j++) w[j] = *(float4*)&Ws[(k + j)*64 + tn];
    #pragma unroll
    for (int kk = 0; kk < 4; kk++) {
      float wv[4] = {w[kk].x, w[kk].y, w[kk].z, w[kk].w};
      float av[4] = {a[0][kk], a[1][kk], a[2][kk], a[3][kk]};
      #pragma unroll
      for (int i = 0; i < 4; i++)
        #pragma unroll
        for (int j = 0; j < 4; j++)
          acc[i][j] = fmaf(av[i], wv[j], acc[i][j]);
    }
  }
  #pragma unroll
  for (int i = 0; i < 4; i++)
    #pragma unroll
    for (int j = 0; j < 4; j++)
      atomicAdd(&Hacc[(size_t)(tmg + i)*DIM + nc + tn + j], acc[i][j]);
}

// ============================ final stage 2: Oacc += relu(Hacc+cb1) @ cw2 (K-split) =======
__global__ __launch_bounds__(256) void fgemm2_kernel(
    const float* __restrict__ Hacc, const float* __restrict__ cb1,
    const float* __restrict__ cw2, float* __restrict__ Oacc)
{
  __shared__ float As[64*132];
  __shared__ float Ws[128*64];
  int t = threadIdx.x;
  int nc = blockIdx.x * 64, kc = blockIdx.y * 128;

  #pragma unroll
  for (int p = 0; p < 8; p++) {
    int i = t + 256*p;
    int m = i >> 5, k0 = (i & 31) << 2;
    float4 v = *(const float4*)&Hacc[(size_t)m*DIM + kc + k0];
    float4 b = *(const float4*)&cb1[kc + k0];
    v.x = fmaxf(v.x + b.x, 0.f); v.y = fmaxf(v.y + b.y, 0.f);
    v.z = fmaxf(v.z + b.z, 0.f); v.w = fmaxf(v.w + b.w, 0.f);
    *(float4*)&As[m*132 + k0] = v;
  }
  #pragma unroll
  for (int p = 0; p < 8; p++) {
    int i = t + 256*p;
    int k = i >> 4, n0 = (i & 15) << 2;
    *(float4*)&Ws[k*64 + n0] = *(const float4*)&cw2[(size_t)(kc + k)*DIM + nc + n0];
  }
  __syncthreads();

  int tn = (t & 15) * 4, tmg = (t >> 4) * 4;
  float acc[4][4];
  #pragma unroll
  for (int i = 0; i < 4; i++)
    #pragma unroll
    for (int j = 0; j < 4; j++) acc[i][j] = 0.f;

  for (int k = 0; k < 128; k += 4) {
    float4 a[4], w[4];
    #pragma unroll
    for (int i = 0; i < 4; i++) a[i] = *(float4*)&As[(tmg + i)*132 + k];
    #pragma unroll
    for (int j = 0; j < 4; j++) w[j] = *(float4*)&Ws[(k + j)*64 + tn];
    #pragma unroll
    for (int kk = 0; kk < 4; kk++) {
      float wv[4] = {w[kk].x, w[kk].y, w[kk].z, w[kk].w};
      float av[4] = {a[0][kk], a[1][kk], a[2][kk], a[3][kk]};
      #pragma unroll
      for (int i = 0; i < 4; i++)
        #pragma unroll
        for (int j = 0; j < 4; j++)
          acc[i][j] = fmaf(av[i], wv[j], acc[i][j]);
    }
  }
  #pragma unroll
  for (int i = 0; i < 4; i++)
    #pragma unroll
    for (int j = 0; j < 4; j++)
      atomicAdd(&Oacc[(size_t)(tmg + i)*DIM + nc + tn + j], acc[i][j]);
}

// ============================ final stage 3: out = Oacc + cb2 =============================
__global__ __launch_bounds__(256) void fbias_kernel(
    const float* __restrict__ Oacc, const float* __restrict__ cb2,
    float* __restrict__ out)
{
  int gi = blockIdx.x * 256 + threadIdx.x;
  out[gi] = Oacc[gi] + cb2[gi & 511];
}

// ============================ launch ======================================================
extern "C" void kernel_launch(void* const* d_in, const int* in_sizes, int n_in,
                              void* d_out, int out_size, void* d_ws, size_t ws_size,
                              hipStream_t stream) {
  const float* feat   = (const float*)d_in[0];
  const int*   labels = (const int*)d_in[1];
  const float* ch_w1  = (const float*)d_in[2];
  const float* ch_b1  = (const float*)d_in[3];
  const float* ch_w2  = (const float*)d_in[4];
  const float* ch_b2  = (const float*)d_in[5];
  const float* ref_w1 = (const float*)d_in[6];
  const float* ref_b1 = (const float*)d_in[7];
  const float* ln_g   = (const float*)d_in[8];
  const float* ln_b   = (const float*)d_in[9];
  const float* ref_w2 = (const float*)d_in[10];
  const float* ref_b2 = (const float*)d_in[11];
  const float* cw1    = (const float*)d_in[12];
  const float* cb1    = (const float*)d_in[13];
  const float* cw2    = (const float*)d_in[14];
  const float* cb2    = (const float*)d_in[15];
  float* out = (float*)d_out;

  float* wsf = (float*)d_ws;
  float* off    = wsf;                    // 32768
  float* lp_all = off + 32768;            // 98304
  // ---- contiguous per-level zeroed region: sums | cnt | mP | Y2 ----
  float* sums   = lp_all + 98304;         // NSEG*DIM = 524288
  int*   cnt_i  = (int*)(sums + 524288);  // NSEG
  float* mP     = (float*)(cnt_i + NSEG); // 2*NSEG (LN partial s1|s2)
  float* Y2     = mP + 2*NSEG;            // 524288 (zeroed: mode-2 K-split atomicAdd)
  // ------------------------------------------------------------------
  float* offW1b = Y2 + 524288;            // 16384
  float* Hacc   = offW1b + 16384;         // 32768
  float* Oacc   = Hacc + 32768;           // 32768
  float* Y1     = Oacc + 32768;           // 524288

  bf16_t* whiT  = (bf16_t*)(Y1 + 524288);
  bf16_t* wloT  = whiT + (size_t)NLVL*HID*DIM;
  bf16_t* r1hiT = wloT + (size_t)NLVL*HID*DIM;
  bf16_t* r1loT = r1hiT + (size_t)NLVL*DIM*DIM;
  bf16_t* r2hiT = r1loT + (size_t)NLVL*DIM*DIM;
  bf16_t* r2loT = r2hiT + (size_t)NLVL*DIM*DIM;
  bf16_t* w2hT  = r2loT + (size_t)NLVL*DIM*DIM;     // [NLVL][KCL][HID]
  bf16_t* w2lT  = w2hT + (size_t)NLVL*KCL*HID;
  int* asg     = (int*)(w2lT + (size_t)NLVL*KCL*HID);
  int* rowlist = asg + NPTS;
  int* seglist = rowlist + NPTS;
  int* seg_st  = seglist + NPTS;       // 1025 used, 1040 reserved
  int* cursor  = seg_st + 1040;        // NSEG

  hipMemsetAsync(off, 0, NCLS*DIM*sizeof(float), stream);

  wsplit_kernel<<<NLVL*HID*DIM/256, 256, 0, stream>>>(ch_w1, whiT, wloT);
  wsplit2_kernel<<<2*NLVL*DIM*DIM/256, 256, 0, stream>>>(
      ref_w1, ref_w2, r1hiT, r1loT, r2hiT, r2loT);
  wsplitW2_kernel<<<NLVL*KCL*HID/256, 256, 0, stream>>>(ch_w2, w2hT, w2lT);

  for (int l = 0; l < NLVL; l++) {
    // zero sums + cnt + mP + Y2 in one shot (contiguous)
    hipMemsetAsync(sums, 0, (524288 + NSEG + 2*NSEG + 524288)*sizeof(float), stream);

    // l=0: off==0 -> offW1b[c] == b1 for all c -> read b1 with row-stride 0
    const float* offsrc = (l == 0) ? ch_b1 : offW1b;
    int ldo = (l == 0) ? 0 : HID;

    // fused GEMM (feat @ W1_l, 3-term hi/lo) + MFMA assign epilogue -> asg, cnt
    gemmassign_kernel<<<NPTS/128, 512, 0, stream>>>(
        feat, whiT + (size_t)l*HID*DIM, wloT + (size_t)l*HID*DIM,
        w2hT + (size_t)l*KCL*HID, w2lT + (size_t)l*KCL*HID,
        offsrc, ldo, labels,
        ch_b2 + (size_t)l*KCL,
        asg, cnt_i);

    scan_kernel<<<1, 256, 0, stream>>>(cnt_i, seg_st, cursor);

    scatter_kernel<<<NPTS/256, 256, 0, stream>>>(labels, asg, cursor, rowlist, seglist);

    means3_kernel<<<dim3(NPTS/64, DIM/256), 256, 0, stream>>>(
        feat, rowlist, seglist, sums);

    // refine: Y1 = meannorm(sums) @ ref_w1 ; epilogue accumulates LN stats into mP
    gemm64_kernel<<<dim3(NSEG/64, DIM/64, 1), 256, 0, stream>>>(
        sums, r1hiT + (size_t)l*DIM*DIM, r1loT + (size_t)l*DIM*DIM, Y1, 1,
        cnt_i, off, ref_b1 + (size_t)l*DIM, nullptr, nullptr, mP);

    // Y2 = relu(LN(Y1+b1)*g+b) @ ref_w2   (K-split z=2, atomicAdd into zeroed Y2)
    gemm64_kernel<<<dim3(NSEG/64, DIM/64, 2), 256, 0, stream>>>(
        Y1, r2hiT + (size_t)l*DIM*DIM, r2loT + (size_t)l*DIM*DIM, Y2, 2,
        nullptr, nullptr, ref_b1 + (size_t)l*DIM,
        ln_g + (size_t)l*DIM, ln_b + (size_t)l*DIM, mP);

    // lp + off update + next level's offW1b (fused); l=2 skips the offgemm part
    protoOffgemm_kernel<<<NCLS, 256, 0, stream>>>(
        Y2, ref_b2 + (size_t)l*DIM, cnt_i, off, lp_all + (size_t)l*NCLS*DIM,
        (l < NLVL-1) ? (ch_w1 + (size_t)(l+1)*DIM*HID) : nullptr,
        (l < NLVL-1) ? (ch_b1 + (size_t)(l+1)*HID) : nullptr,
        offW1b);
  }

  hipMemsetAsync(Hacc, 0, 2*NCLS*DIM*sizeof(float), stream);
  fgemm1_kernel<<<dim3(DIM/64, NLVL*DIM/128), 256, 0, stream>>>(lp_all, cw1, Hacc);
  fgemm2_kernel<<<dim3(DIM/64, DIM/128), 256, 0, stream>>>(Hacc, cb1, cw2, Oacc);
  fbias_kernel<<<NCLS*DIM/256, 256, 0, stream>>>(Oacc, cb2, out);
}

// Round 9
// 742.225 us; speedup vs baseline: 1.2625x; 1.0559x over previous
//
#include <hip/hip_runtime.h>

#define NPTS 65536
#define DIM  512
#define HID  256
#define KCL  16
#define NLVL 3
#define NCLS 64
#define NSEG (NCLS*KCL)
#define EPSF 1e-5f

typedef __bf16 bf16_t;
typedef bf16_t bf16x4 __attribute__((ext_vector_type(4)));
typedef bf16_t bf16x8 __attribute__((ext_vector_type(8)));
typedef float  f32x4  __attribute__((ext_vector_type(4)));

#define LDA 40   // padded LDS row stride in bf16 units
#define LDH2 68  // padded LDS row stride for f32 h-quarter tile (64 + 4 pad)

// ============================ W1 split+transpose (once): W1[l][k][j] -> [(l*256+j)][k] ====
__global__ __launch_bounds__(256) void wsplit_kernel(
    const float* __restrict__ w1, bf16_t* __restrict__ hiT, bf16_t* __restrict__ loT)
{
  int gid = blockIdx.x * 256 + threadIdx.x;   // 0..393215
  int n = gid >> 9, k = gid & 511;
  int l = n >> 8, j = n & 255;
  float v = w1[l*DIM*HID + k*HID + j];
  bf16_t h = (bf16_t)v;
  hiT[gid] = h;
  loT[gid] = (bf16_t)(v - (float)h);
}

// ============================ ref-W split+transpose, both weights in one launch ===========
__global__ __launch_bounds__(256) void wsplit2_kernel(
    const float* __restrict__ w1, const float* __restrict__ w2,
    bf16_t* __restrict__ h1, bf16_t* __restrict__ l1,
    bf16_t* __restrict__ h2, bf16_t* __restrict__ l2)
{
  const int per = NLVL*DIM*DIM;
  int gid = blockIdx.x * 256 + threadIdx.x;   // 0..2*per-1
  const float* w = (gid < per) ? w1 : w2;
  bf16_t* hh = (gid < per) ? h1 : h2;
  bf16_t* ll = (gid < per) ? l1 : l2;
  int g2 = (gid < per) ? gid : gid - per;
  int n512 = g2 >> 9, k = g2 & 511;
  int l = n512 >> 9, n = n512 & 511;
  float v = w[(size_t)l*DIM*DIM + (size_t)k*DIM + n];
  bf16_t h = (bf16_t)v;
  hh[g2] = h;
  ll[g2] = (bf16_t)(v - (float)h);
}

// ============================ cluster-head W2 split+transpose: [l][k][k2] -> [l][k2][k] ===
__global__ __launch_bounds__(256) void wsplitW2_kernel(
    const float* __restrict__ w2, bf16_t* __restrict__ hiT, bf16_t* __restrict__ loT)
{
  int gid = blockIdx.x * 256 + threadIdx.x;   // 0..NLVL*KCL*HID-1 = 12287
  int l = gid >> 12, rem = gid & 4095;
  int k2 = rem >> 8, k = rem & 255;
  float v = w2[(size_t)l*HID*KCL + k*KCL + k2];
  bf16_t h = (bf16_t)v;
  hiT[gid] = h;
  loT[gid] = (bf16_t)(v - (float)h);
}

// ============================ fused per-level GEMM + cluster assign (128x256, 8 waves) ====
// K-loop: acc = feat[128xK] @ W1[Kx256], 3-term hi/lo MFMA (gemm128-proven geometry).
// Epilogue (R4-proven single-buffer): 4 col-quarter passes: h=relu(acc+off) -> LDS f32;
//   logits[128x16] += h @ W2 via 3-term hi/lo MFMA (wave w owns rows w*16..w*16+16);
//   argmax over k2 via width-16 shuffle, first-max tie-break.
__global__ __launch_bounds__(512, 4) void gemmassign_kernel(
    const float* __restrict__ feat,
    const bf16_t* __restrict__ BhiT, const bf16_t* __restrict__ BloT,
    const bf16_t* __restrict__ w2hT, const bf16_t* __restrict__ w2lT,  // [KCL][HID]
    const float* __restrict__ offsrc, int ldo,
    const int* __restrict__ labels,
    const float* __restrict__ pb2,
    int* __restrict__ asg, int* __restrict__ cnt)
{
  // K-loop view: A(hi,lo) 128 rows + B(hi,lo) 256 rows, LDA-padded bf16 = 61440 B.
  // Epilogue view (overlay): hS [128][LDH2] f32 = 34816 B.
  __shared__ __align__(16) unsigned char SMraw[768*LDA*2];
  __shared__ int labs[128];
  bf16_t* SM  = (bf16_t*)SMraw;
  bf16_t* Ahi = SM;
  bf16_t* Alo = SM + 128*LDA;
  bf16_t* Bhi = SM + 256*LDA;
  bf16_t* Blo = SM + 512*LDA;

  const int t = threadIdx.x;
  const int row0 = blockIdx.x * 128;
  const int w = t >> 6, lane = t & 63;
  const int wm = w & 1, wn = w >> 1;
  const int fm = lane & 15, fq = lane >> 4;

  if (t < 128) labs[t] = labels[row0 + t];
  const float pv = pb2[fm];   // per-lane cluster bias (k2 = fm)

  f32x4 acc[4][4];
  #pragma unroll
  for (int i = 0; i < 4; i++)
    #pragma unroll
    for (int j = 0; j < 4; j++)
      #pragma unroll
      for (int r = 0; r < 4; r++) acc[i][j][r] = 0.f;

  for (int kc = 0; kc < DIM; kc += 32) {
    __syncthreads();
    // stage A: 128 rows x 32 k, f32 -> hi/lo bf16 (2 float4 per thread)
    #pragma unroll
    for (int p = 0; p < 2; p++) {
      int idx = t + 512*p;
      int r = idx >> 3, c = idx & 7;
      float4 v = *(const float4*)&feat[(size_t)(row0 + r)*DIM + kc + c*4];
      bf16x4 hi, lo;
      hi[0] = (bf16_t)v.x; lo[0] = (bf16_t)(v.x - (float)hi[0]);
      hi[1] = (bf16_t)v.y; lo[1] = (bf16_t)(v.y - (float)hi[1]);
      hi[2] = (bf16_t)v.z; lo[2] = (bf16_t)(v.z - (float)hi[2]);
      hi[3] = (bf16_t)v.w; lo[3] = (bf16_t)(v.w - (float)hi[3]);
      *(bf16x4*)&Ahi[r*LDA + c*4] = hi;
      *(bf16x4*)&Alo[r*LDA + c*4] = lo;
    }
    // stage B: 256 cols x 32 k, pre-split bf16 (2 bf16x8 per thread per array)
    #pragma unroll
    for (int p = 0; p < 2; p++) {
      int idx = t + 512*p;
      int n = idx >> 2, c = idx & 3;
      *(bf16x8*)&Bhi[n*LDA + c*8] = *(const bf16x8*)&BhiT[(size_t)n*DIM + kc + c*8];
      *(bf16x8*)&Blo[n*LDA + c*8] = *(const bf16x8*)&BloT[(size_t)n*DIM + kc + c*8];
    }
    __syncthreads();

    bf16x8 ah[4], al[4], bh[4], bl[4];
    #pragma unroll
    for (int mt = 0; mt < 4; mt++) {
      int rr = (wm*64 + mt*16 + fm)*LDA + fq*8;
      ah[mt] = *(bf16x8*)&Ahi[rr];
      al[mt] = *(bf16x8*)&Alo[rr];
    }
    #pragma unroll
    for (int nt = 0; nt < 4; nt++) {
      int rr = (wn*64 + nt*16 + fm)*LDA + fq*8;
      bh[nt] = *(bf16x8*)&Bhi[rr];
      bl[nt] = *(bf16x8*)&Blo[rr];
    }
    #pragma unroll
    for (int mt = 0; mt < 4; mt++)
      #pragma unroll
      for (int nt = 0; nt < 4; nt++) {
        acc[mt][nt] = __builtin_amdgcn_mfma_f32_16x16x32_bf16(ah[mt], bh[nt], acc[mt][nt], 0, 0, 0);
        acc[mt][nt] = __builtin_amdgcn_mfma_f32_16x16x32_bf16(ah[mt], bl[nt], acc[mt][nt], 0, 0, 0);
        acc[mt][nt] = __builtin_amdgcn_mfma_f32_16x16x32_bf16(al[mt], bh[nt], acc[mt][nt], 0, 0, 0);
      }
  }

  // ---------------- MFMA-based assign epilogue (4 col-quarter passes) ----------------
  __syncthreads();                       // all LDS tile reads done -> safe to overlay
  float* hS = (float*)SMraw;             // [128][LDH2] f32

  f32x4 lg = {0.f, 0.f, 0.f, 0.f};       // logits C-frag: row=w*16+fq*4+r, col(k2)=fm

  #pragma unroll
  for (int q = 0; q < 4; q++) {
    // write phase: the 2 waves with wn==q own cols [q*64, q*64+64)
    if (wn == q) {
      #pragma unroll
      for (int nt = 0; nt < 4; nt++) {
        int colq = nt*16 + fm;           // col within quarter
        int colg = q*64 + colq;          // global hidden col
        #pragma unroll
        for (int mt = 0; mt < 4; mt++)
          #pragma unroll
          for (int r = 0; r < 4; r++) {
            int row = wm*64 + mt*16 + fq*4 + r;
            float hv = fmaxf(acc[mt][nt][r] +
                             offsrc[(size_t)labs[row]*ldo + colg], 0.f);
            hS[row*LDH2 + colq] = hv;
          }
      }
    }
    __syncthreads();

    // MFMA phase: wave w -> logits rows [w*16, w*16+16) over this quarter's 64 k-cols
    #pragma unroll
    for (int s = 0; s < 2; s++) {
      int kb = s*32 + fq*8;              // k within quarter
      f32x4 a0 = *(f32x4*)&hS[(w*16 + fm)*LDH2 + kb];
      f32x4 a1 = *(f32x4*)&hS[(w*16 + fm)*LDH2 + kb + 4];
      bf16x8 ahf, alf;
      #pragma unroll
      for (int j = 0; j < 4; j++) {
        bf16_t h0 = (bf16_t)a0[j]; ahf[j]   = h0; alf[j]   = (bf16_t)(a0[j] - (float)h0);
        bf16_t h1 = (bf16_t)a1[j]; ahf[4+j] = h1; alf[4+j] = (bf16_t)(a1[j] - (float)h1);
      }
      bf16x8 bhf = *(const bf16x8*)&w2hT[fm*HID + q*64 + kb];
      bf16x8 blf = *(const bf16x8*)&w2lT[fm*HID + q*64 + kb];
      lg = __builtin_amdgcn_mfma_f32_16x16x32_bf16(ahf, bhf, lg, 0, 0, 0);
      lg = __builtin_amdgcn_mfma_f32_16x16x32_bf16(ahf, blf, lg, 0, 0, 0);
      lg = __builtin_amdgcn_mfma_f32_16x16x32_bf16(alf, bhf, lg, 0, 0, 0);
    }
    __syncthreads();                     // reads done before next quarter's writes
  }

  // argmax over k2 (= fm lanes), first-max tie-break, then scatter asg/cnt
  #pragma unroll
  for (int r = 0; r < 4; r++) {
    float v = lg[r] + pv;
    int idx = fm;
    #pragma unroll
    for (int ofs = 8; ofs > 0; ofs >>= 1) {
      float ov = __shfl_xor(v, ofs, 16);
      int   oi = __shfl_xor(idx, ofs, 16);
      if (ov > v || (ov == v && oi < idx)) { v = ov; idx = oi; }
    }
    if (fm == 0) {
      int rloc = w*16 + fq*4 + r;
      asg[row0 + rloc] = idx;
      atomicAdd(&cnt[labs[rloc]*KCL + idx], 1);
    }
  }
}

// ============================ refine GEMM (templated): 64-row tile, 4-term hi/lo =========
// MODE 1 (CT=1, 32-col tiles, grid (16,16,1) = 256 blocks -> full GPU):
//   A[row][k] = (sums[row][k] + cnt[row]*off[cls][k]) / max(cnt,1); plain C store;
//   epilogue: LN partial stats of (Y1+b1) -> atomicAdd mP[row], mP[NSEG+row].
// MODE 2 (CT=2, 64-col tiles, grid (16,8,2): K-split over z, atomicAdd into zeroed C):
//   A[row][k] = relu((Y1[row][k] + b1[k] - m) * rsqrt(var+eps) * g[k] + bb[k]),
//   m/var derived inline from mP.
template<int MODE, int CT>
__global__ __launch_bounds__(256) void gemm64t_kernel(
    const float* __restrict__ Asrc,
    const bf16_t* __restrict__ BhiT, const bf16_t* __restrict__ BloT,
    float* __restrict__ C,
    const int* __restrict__ cnt, const float* __restrict__ off,
    const float* __restrict__ b1, const float* __restrict__ g,
    const float* __restrict__ bb, float* __restrict__ mP)
{
  constexpr int BC = CT * 32;          // cols per block
  __shared__ __align__(16) bf16_t Ahi[64*LDA];
  __shared__ __align__(16) bf16_t Alo[64*LDA];
  __shared__ __align__(16) bf16_t Bhi[BC*LDA];
  __shared__ __align__(16) bf16_t Blo[BC*LDA];
  __shared__ float rm[64], rr_[64];

  const int t = threadIdx.x;
  const int row0 = blockIdx.x * 64, col0 = blockIdx.y * BC;
  const int w = t >> 6, lane = t & 63;
  const int wm = w & 1, wn = w >> 1;
  const int fm = lane & 15, fq = lane >> 4;

  if (t < 64) {
    if constexpr (MODE == 1) {
      int n = cnt[row0 + t];
      rm[t] = (float)n;
      rr_[t] = 1.f / fmaxf((float)n, 1.f);
    } else {
      float s1 = mP[row0 + t], s2 = mP[NSEG + row0 + t];
      float m = s1 * (1.f/512.f);
      float var = s2 * (1.f/512.f) - m*m;
      rm[t] = m;
      rr_[t] = rsqrtf(var + EPSF);
    }
  }

  f32x4 acc[2][CT];
  #pragma unroll
  for (int i = 0; i < 2; i++)
    #pragma unroll
    for (int j = 0; j < CT; j++)
      #pragma unroll
      for (int r = 0; r < 4; r++) acc[i][j][r] = 0.f;

  const int kstart = (MODE == 2) ? blockIdx.z * 256 : 0;
  const int kend   = (MODE == 2) ? kstart + 256 : DIM;

  for (int kc = kstart; kc < kend; kc += 32) {
    __syncthreads();
    #pragma unroll
    for (int p = 0; p < 2; p++) {
      int idx = t + 256*p;
      int r = idx >> 3, c = idx & 7;
      float4 v = *(const float4*)&Asrc[(size_t)(row0 + r)*DIM + kc + c*4];
      if constexpr (MODE == 1) {
        int cls = (row0 + r) >> 4;
        float4 o = *(const float4*)&off[(size_t)cls*DIM + kc + c*4];
        float n = rm[r], inv = rr_[r];
        v.x = (v.x + n*o.x) * inv; v.y = (v.y + n*o.y) * inv;
        v.z = (v.z + n*o.z) * inv; v.w = (v.w + n*o.w) * inv;
      } else {
        float4 B1 = *(const float4*)&b1[kc + c*4];
        float4 G4 = *(const float4*)&g[kc + c*4];
        float4 BB = *(const float4*)&bb[kc + c*4];
        float m = rm[r], rs = rr_[r];
        v.x = fmaxf((v.x + B1.x - m)*rs*G4.x + BB.x, 0.f);
        v.y = fmaxf((v.y + B1.y - m)*rs*G4.y + BB.y, 0.f);
        v.z = fmaxf((v.z + B1.z - m)*rs*G4.z + BB.z, 0.f);
        v.w = fmaxf((v.w + B1.w - m)*rs*G4.w + BB.w, 0.f);
      }
      bf16x4 hi, lo;
      hi[0] = (bf16_t)v.x; lo[0] = (bf16_t)(v.x - (float)hi[0]);
      hi[1] = (bf16_t)v.y; lo[1] = (bf16_t)(v.y - (float)hi[1]);
      hi[2] = (bf16_t)v.z; lo[2] = (bf16_t)(v.z - (float)hi[2]);
      hi[3] = (bf16_t)v.w; lo[3] = (bf16_t)(v.w - (float)hi[3]);
      *(bf16x4*)&Ahi[r*LDA + c*4] = hi;
      *(bf16x4*)&Alo[r*LDA + c*4] = lo;
    }
    if constexpr (CT == 2) {
      int n = t >> 2, kof = (t & 3)*8;
      *(bf16x8*)&Bhi[n*LDA + kof] = *(const bf16x8*)&BhiT[(size_t)(col0 + n)*DIM + kc + kof];
      *(bf16x8*)&Blo[n*LDA + kof] = *(const bf16x8*)&BloT[(size_t)(col0 + n)*DIM + kc + kof];
    } else {
      int n = t >> 3, kof = (t & 7)*4;
      *(bf16x4*)&Bhi[n*LDA + kof] = *(const bf16x4*)&BhiT[(size_t)(col0 + n)*DIM + kc + kof];
      *(bf16x4*)&Blo[n*LDA + kof] = *(const bf16x4*)&BloT[(size_t)(col0 + n)*DIM + kc + kof];
    }
    __syncthreads();

    bf16x8 ah[2], al[2], bh[CT], bl[CT];
    #pragma unroll
    for (int mt = 0; mt < 2; mt++) {
      int idx = (wm*32 + mt*16 + fm)*LDA + fq*8;
      ah[mt] = *(bf16x8*)&Ahi[idx];
      al[mt] = *(bf16x8*)&Alo[idx];
    }
    #pragma unroll
    for (int nt = 0; nt < CT; nt++) {
      int idx = (wn*(CT*16) + nt*16 + fm)*LDA + fq*8;
      bh[nt] = *(bf16x8*)&Bhi[idx];
      bl[nt] = *(bf16x8*)&Blo[idx];
    }
    #pragma unroll
    for (int mt = 0; mt < 2; mt++)
      #pragma unroll
      for (int nt = 0; nt < CT; nt++) {
        acc[mt][nt] = __builtin_amdgcn_mfma_f32_16x16x32_bf16(ah[mt], bh[nt], acc[mt][nt], 0, 0, 0);
        acc[mt][nt] = __builtin_amdgcn_mfma_f32_16x16x32_bf16(ah[mt], bl[nt], acc[mt][nt], 0, 0, 0);
        acc[mt][nt] = __builtin_amdgcn_mfma_f32_16x16x32_bf16(al[mt], bh[nt], acc[mt][nt], 0, 0, 0);
        acc[mt][nt] = __builtin_amdgcn_mfma_f32_16x16x32_bf16(al[mt], bl[nt], acc[mt][nt], 0, 0, 0);
      }
  }

  #pragma unroll
  for (int mt = 0; mt < 2; mt++)
    #pragma unroll
    for (int nt = 0; nt < CT; nt++) {
      int col = col0 + wn*(CT*16) + nt*16 + fm;
      int rowb = row0 + wm*32 + mt*16 + fq*4;
      #pragma unroll
      for (int r = 0; r < 4; r++) {
        if constexpr (MODE == 2)
          atomicAdd(&C[(size_t)(rowb + r)*DIM + col], acc[mt][nt][r]);
        else
          C[(size_t)(rowb + r)*DIM + col] = acc[mt][nt][r];
      }
    }

  // LN partial stats (MODE 1 only): per-row sums of (Y1+b1) and (Y1+b1)^2 over this
  // block's BC cols; 16-lane shuffle tree then one atomic pair per (row, wave).
  if constexpr (MODE == 1) {
    float b1v[CT];
    #pragma unroll
    for (int nt = 0; nt < CT; nt++) b1v[nt] = b1[col0 + wn*(CT*16) + nt*16 + fm];
    #pragma unroll
    for (int mt = 0; mt < 2; mt++)
      #pragma unroll
      for (int r = 0; r < 4; r++) {
        float c1 = 0.f, c2 = 0.f;
        #pragma unroll
        for (int nt = 0; nt < CT; nt++) {
          float v = acc[mt][nt][r] + b1v[nt];
          c1 += v; c2 += v*v;
        }
        #pragma unroll
        for (int ofs = 8; ofs > 0; ofs >>= 1) {
          c1 += __shfl_xor(c1, ofs, 16);
          c2 += __shfl_xor(c2, ofs, 16);
        }
        if (fm == 0) {
          int row = row0 + wm*32 + mt*16 + fq*4 + r;
          atomicAdd(&mP[row], c1);
          atomicAdd(&mP[NSEG + row], c2);
        }
      }
  }
}

// ============================ offW1b[c][j] = off[c]@W1_l[:,j] + b1[j] (l=0 handled by ldo=0)
// fused: lp[c] = mean over non-empty k of Y2 + b2; off += lp; zero own cnt (last reader);
// then next-level offgemm.
__global__ __launch_bounds__(256) void protoOffgemm_kernel(
    const float* __restrict__ Y2, const float* __restrict__ b2,
    int* __restrict__ cnt, float* __restrict__ off, float* __restrict__ lp_out,
    const float* __restrict__ w1next, const float* __restrict__ b1next,
    float* __restrict__ offW1b)
{
  __shared__ float offs[DIM];
  int c = blockIdx.x, t = threadIdx.x;
  int nes = 0;
  #pragma unroll
  for (int k = 0; k < KCL; k++) nes += (cnt[c*KCL + k] > 0);
  float inv = 1.f / (float)nes;
  #pragma unroll
  for (int h = 0; h < 2; h++) {
    int d = t + h*256;
    float s = 0.f;
    #pragma unroll
    for (int k = 0; k < KCL; k++)
      if (cnt[c*KCL + k] > 0) s += Y2[(size_t)(c*KCL + k)*DIM + d];
    float lp = s * inv + b2[d];
    lp_out[c*DIM + d] = lp;
    float on = off[c*DIM + d] + lp;
    off[c*DIM + d] = on;
    offs[d] = on;
  }
  __syncthreads();                       // all cnt reads + offs writes complete
  if (t < KCL) cnt[c*KCL + t] = 0;       // zero own counters for next level
  if (w1next == nullptr) return;
  // 4 independent accumulators to break the serial fmaf dependency chain
  float a0 = 0.f, a1 = 0.f, a2 = 0.f, a3 = 0.f;
  #pragma unroll 4
  for (int d = 0; d < DIM; d += 4) {
    a0 = fmaf(offs[d+0], w1next[(d+0)*HID + t], a0);
    a1 = fmaf(offs[d+1], w1next[(d+1)*HID + t], a1);
    a2 = fmaf(offs[d+2], w1next[(d+2)*HID + t], a2);
    a3 = fmaf(offs[d+3], w1next[(d+3)*HID + t], a3);
  }
  offW1b[c*HID + t] = ((a0 + a1) + (a2 + a3)) + b1next[t];
}

// ============================ exclusive scan (shuffle-based) ==============================
__global__ void scan_kernel(const int* __restrict__ cnt, int* __restrict__ seg_st,
                            int* __restrict__ cursor)
{
  int t = threadIdx.x;
  int4 v = *(const int4*)&cnt[t*4];
  int a0 = v.x, a1 = v.x + v.y, a2 = a1 + v.z, tot = a2 + v.w;
  int lane = t & 63, w = t >> 6;
  int sc = tot;
  #pragma unroll
  for (int ofs = 1; ofs < 64; ofs <<= 1) {
    int u = __shfl_up(sc, ofs);
    if (lane >= ofs) sc += u;
  }
  __shared__ int wt[4];
  if (lane == 63) wt[w] = sc;
  __syncthreads();
  int base = 0;
  #pragma unroll
  for (int i = 0; i < 4; i++) if (i < w) base += wt[i];
  int excl = base + sc - tot;
  seg_st[t*4 + 1] = excl + a0;
  seg_st[t*4 + 2] = excl + a1;
  seg_st[t*4 + 3] = excl + a2;
  seg_st[t*4 + 4] = excl + tot;
  if (t == 0) seg_st[0] = 0;
  int4 cur = {excl, excl + a0, excl + a1, excl + a2};
  *(int4*)&cursor[t*4] = cur;
}

// ============================ scatter rows + zero next-phase buffers ======================
// 65536 threads: each zeroes 8 f32 of sums and 8 of Y2 (first 512 also zero mP),
// then scatters its row. Replaces the per-level hipMemsetAsync dispatch.
__global__ __launch_bounds__(256) void scatter_kernel(
    const int* __restrict__ labels, const int* __restrict__ asg,
    int* __restrict__ cursor, int* __restrict__ rowlist, int* __restrict__ seglist,
    float* __restrict__ zsums, float* __restrict__ zY2, float* __restrict__ zmP)
{
  int i = blockIdx.x * 256 + threadIdx.x;
  float4 z = {0.f, 0.f, 0.f, 0.f};
  *(float4*)&zsums[(size_t)i*8]     = z;
  *(float4*)&zsums[(size_t)i*8 + 4] = z;
  *(float4*)&zY2[(size_t)i*8]       = z;
  *(float4*)&zY2[(size_t)i*8 + 4]   = z;
  if (i < 512) *(float4*)&zmP[i*4] = z;
  int seg = labels[i]*KCL + asg[i];
  int pos = atomicAdd(&cursor[seg], 1);
  rowlist[pos] = i;
  seglist[pos] = seg;
}

// ============================ balanced segmented sums over sorted rowlist =================
__global__ __launch_bounds__(256) void means3_kernel(
    const float* __restrict__ feat, const int* __restrict__ rowlist,
    const int* __restrict__ seglist, float* __restrict__ sums)
{
  __shared__ int rows[64];
  __shared__ int segs[65];
  int t = threadIdx.x;
  int i0 = blockIdx.x * 64;
  int col = blockIdx.y * 256 + t;
  if (t < 64) { rows[t] = rowlist[i0 + t]; segs[t] = seglist[i0 + t]; }
  if (t == 64) segs[64] = -1;
  __syncthreads();
  float acc = 0.f;
  for (int base = 0; base < 64; base += 16) {
    float v[16];
    #pragma unroll
    for (int j = 0; j < 16; j++)
      v[j] = feat[(size_t)rows[base + j]*DIM + col];
    #pragma unroll
    for (int j = 0; j < 16; j++) {
      acc += v[j];
      if (segs[base + j] != segs[base + j + 1]) {
        atomicAdd(&sums[(size_t)segs[base + j]*DIM + col], acc);
        acc = 0.f;
      }
    }
  }
}

// ============================ final stage 1: Hacc += comb[64x1536] @ cw1 (K-split) ========
__global__ __launch_bounds__(256) void fgemm1_kernel(
    const float* __restrict__ lp_all, const float* __restrict__ cw1,
    float* __restrict__ Hacc)
{
  __shared__ float As[64*132];
  __shared__ float Ws[128*64];
  int t = threadIdx.x;
  int nc = blockIdx.x * 64, kc = blockIdx.y * 128;

  #pragma unroll
  for (int p = 0; p < 8; p++) {
    int i = t + 256*p;
    int m = i >> 5, k0 = (i & 31) << 2;
    int k = kc + k0;
    int l = k >> 9, d = k & 511;
    *(float4*)&As[m*132 + k0] = *(const float4*)&lp_all[(size_t)(l*NCLS + m)*DIM + d];
  }
  #pragma unroll
  for (int p = 0; p < 8; p++) {
    int i = t + 256*p;
    int k = i >> 4, n0 = (i & 15) << 2;
    *(float4*)&Ws[k*64 + n0] = *(const float4*)&cw1[(size_t)(kc + k)*DIM + nc + n0];
  }
  __syncthreads();

  int tn = (t & 15) * 4, tmg = (t >> 4) * 4;
  float acc[4][4];
  #pragma unroll
  for (int i = 0; i < 4; i++)
    #pragma unroll
    for (int j = 0; j < 4; j++) acc[i][j] = 0.f;

  for (int k = 0; k < 128; k += 4) {
    float4 a[4], w[4];
    #pragma unroll
    for (int i = 0; i < 4; i++) a[i] = *(float4*)&As[(tmg + i)*132 + k];
    #pragma unroll
    for (int j = 0; j < 4; j++) w[j] = *(float4*)&Ws[(k + j)*64 + tn];
    #pragma unroll
    for (int kk = 0; kk < 4; kk++) {
      float wv[4] = {w[kk].x, w[kk].y, w[kk].z, w[kk].w};
      float av[4] = {a[0][kk], a[1][kk], a[2][kk], a[3][kk]};
      #pragma unroll
      for (int i = 0; i < 4; i++)
        #pragma unroll
        for (int j = 0; j < 4; j++)
          acc[i][j] = fmaf(av[i], wv[j], acc[i][j]);
    }
  }
  #pragma unroll
  for (int i = 0; i < 4; i++)
    #pragma unroll
    for (int j = 0; j < 4; j++)
      atomicAdd(&Hacc[(size_t)(tmg + i)*DIM + nc + tn + j], acc[i][j]);
}

// ============================ final stage 2: Oacc += relu(Hacc+cb1) @ cw2 (K-split) =======
__global__ __launch_bounds__(256) void fgemm2_kernel(
    const float* __restrict__ Hacc, const float* __restrict__ cb1,
    const float* __restrict__ cw2, float* __restrict__ Oacc)
{
  __shared__ float As[64*132];
  __shared__ float Ws[128*64];
  int t = threadIdx.x;
  int nc = blockIdx.x * 64, kc = blockIdx.y * 128;

  #pragma unroll
  for (int p = 0; p < 8; p++) {
    int i = t + 256*p;
    int m = i >> 5, k0 = (i & 31) << 2;
    float4 v = *(const float4*)&Hacc[(size_t)m*DIM + kc + k0];
    float4 b = *(const float4*)&cb1[kc + k0];
    v.x = fmaxf(v.x + b.x, 0.f); v.y = fmaxf(v.y + b.y, 0.f);
    v.z = fmaxf(v.z + b.z, 0.f); v.w = fmaxf(v.w + b.w, 0.f);
    *(float4*)&As[m*132 + k0] = v;
  }
  #pragma unroll
  for (int p = 0; p < 8; p++) {
    int i = t + 256*p;
    int k = i >> 4, n0 = (i & 15) << 2;
    *(float4*)&Ws[k*64 + n0] = *(const float4*)&cw2[(size_t)(kc + k)*DIM + nc + n0];
  }
  __syncthreads();

  int tn = (t & 15) * 4, tmg = (t >> 4) * 4;
  float acc[4][4];
  #pragma unroll
  for (int i = 0; i < 4; i++)
    #pragma unroll
    for (int j = 0; j < 4; j++) acc[i][j] = 0.f;

  for (int k = 0; k < 128; k += 4) {
    float4 a[4], w[4];
    #pragma unroll
    for (int i = 0; i < 4; i++) a[i] = *(float4*)&As[(tmg + i)*132 + k];
    #pragma unroll
    for (int j = 0; j < 4; j++) w[j] = *(float4*)&Ws[(k + j)*64 + tn];
    #pragma unroll
    for (int kk = 0; kk < 4; kk++) {
      float wv[4] = {w[kk].x, w[kk].y, w[kk].z, w[kk].w};
      float av[4] = {a[0][kk], a[1][kk], a[2][kk], a[3][kk]};
      #pragma unroll
      for (int i = 0; i < 4; i++)
        #pragma unroll
        for (int j = 0; j < 4; j++)
          acc[i][j] = fmaf(av[i], wv[j], acc[i][j]);
    }
  }
  #pragma unroll
  for (int i = 0; i < 4; i++)
    #pragma unroll
    for (int j = 0; j < 4; j++)
      atomicAdd(&Oacc[(size_t)(tmg + i)*DIM + nc + tn + j], acc[i][j]);
}

// ============================ final stage 3: out = Oacc + cb2 =============================
__global__ __launch_bounds__(256) void fbias_kernel(
    const float* __restrict__ Oacc, const float* __restrict__ cb2,
    float* __restrict__ out)
{
  int gi = blockIdx.x * 256 + threadIdx.x;
  out[gi] = Oacc[gi] + cb2[gi & 511];
}

// ============================ launch ======================================================
extern "C" void kernel_launch(void* const* d_in, const int* in_sizes, int n_in,
                              void* d_out, int out_size, void* d_ws, size_t ws_size,
                              hipStream_t stream) {
  const float* feat   = (const float*)d_in[0];
  const int*   labels = (const int*)d_in[1];
  const float* ch_w1  = (const float*)d_in[2];
  const float* ch_b1  = (const float*)d_in[3];
  const float* ch_w2  = (const float*)d_in[4];
  const float* ch_b2  = (const float*)d_in[5];
  const float* ref_w1 = (const float*)d_in[6];
  const float* ref_b1 = (const float*)d_in[7];
  const float* ln_g   = (const float*)d_in[8];
  const float* ln_b   = (const float*)d_in[9];
  const float* ref_w2 = (const float*)d_in[10];
  const float* ref_b2 = (const float*)d_in[11];
  const float* cw1    = (const float*)d_in[12];
  const float* cb1    = (const float*)d_in[13];
  const float* cw2    = (const float*)d_in[14];
  const float* cb2    = (const float*)d_in[15];
  float* out = (float*)d_out;

  float* wsf = (float*)d_ws;
  float* off    = wsf;                    // 32768
  float* lp_all = off + 32768;            // 98304
  // ---- contiguous per-level zeroed region: sums | cnt | mP | Y2 ----
  float* sums   = lp_all + 98304;         // NSEG*DIM = 524288
  int*   cnt_i  = (int*)(sums + 524288);  // NSEG
  float* mP     = (float*)(cnt_i + NSEG); // 2*NSEG (LN partial s1|s2)
  float* Y2     = mP + 2*NSEG;            // 524288 (zeroed: mode-2 K-split atomicAdd)
  // ------------------------------------------------------------------
  float* offW1b = Y2 + 524288;            // 16384
  float* Hacc   = offW1b + 16384;         // 32768
  float* Oacc   = Hacc + 32768;           // 32768
  float* Y1     = Oacc + 32768;           // 524288

  bf16_t* whiT  = (bf16_t*)(Y1 + 524288);
  bf16_t* wloT  = whiT + (size_t)NLVL*HID*DIM;
  bf16_t* r1hiT = wloT + (size_t)NLVL*HID*DIM;
  bf16_t* r1loT = r1hiT + (size_t)NLVL*DIM*DIM;
  bf16_t* r2hiT = r1loT + (size_t)NLVL*DIM*DIM;
  bf16_t* r2loT = r2hiT + (size_t)NLVL*DIM*DIM;
  bf16_t* w2hT  = r2loT + (size_t)NLVL*DIM*DIM;     // [NLVL][KCL][HID]
  bf16_t* w2lT  = w2hT + (size_t)NLVL*KCL*HID;
  int* asg     = (int*)(w2lT + (size_t)NLVL*KCL*HID);
  int* rowlist = asg + NPTS;
  int* seglist = rowlist + NPTS;
  int* seg_st  = seglist + NPTS;       // 1025 used, 1040 reserved
  int* cursor  = seg_st + 1040;        // NSEG

  hipMemsetAsync(off, 0, NCLS*DIM*sizeof(float), stream);
  hipMemsetAsync(cnt_i, 0, NSEG*sizeof(int), stream);   // level-0 cnt init (one-time)

  wsplit_kernel<<<NLVL*HID*DIM/256, 256, 0, stream>>>(ch_w1, whiT, wloT);
  wsplit2_kernel<<<2*NLVL*DIM*DIM/256, 256, 0, stream>>>(
      ref_w1, ref_w2, r1hiT, r1loT, r2hiT, r2loT);
  wsplitW2_kernel<<<NLVL*KCL*HID/256, 256, 0, stream>>>(ch_w2, w2hT, w2lT);

  for (int l = 0; l < NLVL; l++) {
    // l=0: off==0 -> offW1b[c] == b1 for all c -> read b1 with row-stride 0
    const float* offsrc = (l == 0) ? ch_b1 : offW1b;
    int ldo = (l == 0) ? 0 : HID;

    // fused GEMM (feat @ W1_l, 3-term hi/lo) + MFMA assign epilogue -> asg, cnt
    gemmassign_kernel<<<NPTS/128, 512, 0, stream>>>(
        feat, whiT + (size_t)l*HID*DIM, wloT + (size_t)l*HID*DIM,
        w2hT + (size_t)l*KCL*HID, w2lT + (size_t)l*KCL*HID,
        offsrc, ldo, labels,
        ch_b2 + (size_t)l*KCL,
        asg, cnt_i);

    scan_kernel<<<1, 256, 0, stream>>>(cnt_i, seg_st, cursor);

    // scatter + zero sums/Y2/mP for this level (replaces per-level memset)
    scatter_kernel<<<NPTS/256, 256, 0, stream>>>(
        labels, asg, cursor, rowlist, seglist, sums, Y2, mP);

    means3_kernel<<<dim3(NPTS/64, DIM/256), 256, 0, stream>>>(
        feat, rowlist, seglist, sums);

    // refine: Y1 = meannorm(sums) @ ref_w1 ; epilogue accumulates LN stats into mP
    // 32-col tiles -> 256 blocks (full GPU)
    gemm64t_kernel<1,1><<<dim3(NSEG/64, DIM/32, 1), 256, 0, stream>>>(
        sums, r1hiT + (size_t)l*DIM*DIM, r1loT + (size_t)l*DIM*DIM, Y1,
        cnt_i, off, ref_b1 + (size_t)l*DIM, nullptr, nullptr, mP);

    // Y2 = relu(LN(Y1+b1)*g+b) @ ref_w2   (K-split z=2, atomicAdd into zeroed Y2)
    gemm64t_kernel<2,2><<<dim3(NSEG/64, DIM/64, 2), 256, 0, stream>>>(
        Y1, r2hiT + (size_t)l*DIM*DIM, r2loT + (size_t)l*DIM*DIM, Y2,
        nullptr, nullptr, ref_b1 + (size_t)l*DIM,
        ln_g + (size_t)l*DIM, ln_b + (size_t)l*DIM, mP);

    // lp + off update + cnt re-zero + next level's offW1b (fused)
    protoOffgemm_kernel<<<NCLS, 256, 0, stream>>>(
        Y2, ref_b2 + (size_t)l*DIM, cnt_i, off, lp_all + (size_t)l*NCLS*DIM,
        (l < NLVL-1) ? (ch_w1 + (size_t)(l+1)*DIM*HID) : nullptr,
        (l < NLVL-1) ? (ch_b1 + (size_t)(l+1)*HID) : nullptr,
        offW1b);
  }

  hipMemsetAsync(Hacc, 0, 2*NCLS*DIM*sizeof(float), stream);
  fgemm1_kernel<<<dim3(DIM/64, NLVL*DIM/128), 256, 0, stream>>>(lp_all, cw1, Hacc);
  fgemm2_kernel<<<dim3(DIM/64, DIM/128), 256, 0, stream>>>(Hacc, cb1, cw2, Oacc);
  fbias_kernel<<<NCLS*DIM/256, 256, 0, stream>>>(Oacc, cb2, out);
}